// Round 22
// baseline (4919.603 us; speedup 1.0000x reference)
//
#include <hip/hip_runtime.h>
#include <hip/hip_bf16.h>

typedef unsigned short u16;
typedef __bf16 bf16x8 __attribute__((ext_vector_type(8)));
typedef unsigned short ushort8v __attribute__((ext_vector_type(8)));
typedef float f32x4 __attribute__((ext_vector_type(4)));
typedef float f32x8 __attribute__((ext_vector_type(8)));

#define B_ 4
#define T_ 2048
#define C_ 2048
#define H_ 32
#define S_ 64

__device__ __forceinline__ u16 f2bf(float x) {
  __bf16 b = (__bf16)x;  // native RNE conversion
  return __builtin_bit_cast(u16, b);
}
__device__ __forceinline__ float bf2f(u16 x) {
  return __uint_as_float(((unsigned int)x) << 16);
}
__device__ __forceinline__ void gload_lds16(const void* g, void* l) {
  __builtin_amdgcn_global_load_lds(
      (const __attribute__((address_space(1))) void*)g,
      (__attribute__((address_space(3))) void*)l, 16, 0, 0);
}

#define VM10 asm volatile("s_waitcnt vmcnt(10)" ::: "memory")
#define VM8 asm volatile("s_waitcnt vmcnt(8)" ::: "memory")
#define VM0 asm volatile("s_waitcnt vmcnt(0)" ::: "memory")
#define LGKM0 asm volatile("s_waitcnt lgkmcnt(0)" ::: "memory")
#define BARR __builtin_amdgcn_s_barrier()
#define SCB __builtin_amdgcn_sched_barrier(0)

// ---------------- single mix + cast to bf16 (fallback path) ----------------
__global__ __launch_bounds__(256) void mix_cast_kernel(
    const float* __restrict__ hidden, const float* __restrict__ mixp,
    u16* __restrict__ out) {
  int idx = blockIdx.x * 256 + threadIdx.x;
  int c4 = idx & 511;
  int bt = idx >> 9;
  int t = bt & (T_ - 1);
  float4 h = reinterpret_cast<const float4*>(hidden)[idx];
  float4 m = reinterpret_cast<const float4*>(mixp)[c4];
  float4 sh = make_float4(0.f, 0.f, 0.f, 0.f);
  if (t != 0) sh = reinterpret_cast<const float4*>(hidden)[idx - 512];
  ushort4 o;
  o.x = f2bf(h.x * m.x + sh.x * (1.f - m.x));
  o.y = f2bf(h.y * m.y + sh.y * (1.f - m.y));
  o.z = f2bf(h.z * m.z + sh.z * (1.f - m.z));
  o.w = f2bf(h.w * m.w + sh.w * (1.f - m.w));
  reinterpret_cast<ushort4*>(out)[idx] = o;
}

// ---------------- fused 4-way mix + cast, row-paired (1.5 reads/row) ----------------
__global__ __launch_bounds__(256) void mix4p_cast_kernel(
    const float* __restrict__ hidden,
    const float* __restrict__ mK, const float* __restrict__ mV,
    const float* __restrict__ mR, const float* __restrict__ mG,
    u16* __restrict__ oK, u16* __restrict__ oV,
    u16* __restrict__ oR, u16* __restrict__ oG) {
  int bid = blockIdx.x;            // 8192 = (B*T/2) * 2 col-halves
  int colh = bid & 1;
  int rp = bid >> 1;               // row pair index
  int c4 = colh * 256 + threadIdx.x;   // 0..511
  int bt0 = rp * 2;
  int t0 = bt0 & (T_ - 1);
  size_t i0 = (size_t)bt0 * 512 + c4;
  float4 h0 = reinterpret_cast<const float4*>(hidden)[i0];
  float4 h1 = reinterpret_cast<const float4*>(hidden)[i0 + 512];
  float4 hp = make_float4(0.f, 0.f, 0.f, 0.f);
  if (t0 != 0) hp = reinterpret_cast<const float4*>(hidden)[i0 - 512];
  float4 m;
  ushort4 o0, o1;
#define DOMIX2(MP, OP)                                           \
  m = reinterpret_cast<const float4*>(MP)[c4];                   \
  o0.x = f2bf(h0.x * m.x + hp.x * (1.f - m.x));                  \
  o0.y = f2bf(h0.y * m.y + hp.y * (1.f - m.y));                  \
  o0.z = f2bf(h0.z * m.z + hp.z * (1.f - m.z));                  \
  o0.w = f2bf(h0.w * m.w + hp.w * (1.f - m.w));                  \
  o1.x = f2bf(h1.x * m.x + h0.x * (1.f - m.x));                  \
  o1.y = f2bf(h1.y * m.y + h0.y * (1.f - m.y));                  \
  o1.z = f2bf(h1.z * m.z + h0.z * (1.f - m.z));                  \
  o1.w = f2bf(h1.w * m.w + h0.w * (1.f - m.w));                  \
  reinterpret_cast<ushort4*>(OP)[i0] = o0;                       \
  reinterpret_cast<ushort4*>(OP)[i0 + 512] = o1;
  DOMIX2(mK, oK)
  DOMIX2(mV, oV)
  DOMIX2(mR, oR)
  DOMIX2(mG, oG)
#undef DOMIX2
}

// ---------------- fp32 -> bf16 weight cast ----------------
__global__ __launch_bounds__(256) void conv_bf16_kernel(
    const float* __restrict__ in, u16* __restrict__ out, int n4) {
  int i = blockIdx.x * 256 + threadIdx.x;
  if (i >= n4) return;
  float4 v = reinterpret_cast<const float4*>(in)[i];
  ushort4 o;
  o.x = f2bf(v.x); o.y = f2bf(v.y); o.z = f2bf(v.z); o.w = f2bf(v.w);
  reinterpret_cast<ushort4*>(out)[i] = o;
}

// ---------------- 256x256 bf16 GEMM (4-slot r20 schedule + wave-staggered
// LOADF/MM ordering: even waves MM-then-LOADF, odd waves LOADF-then-MM) ------
template <typename OT>
__global__ __launch_bounds__(512, 2) void gemm_bt256(
    const u16* __restrict__ A, const u16* __restrict__ Bm,
    OT* __restrict__ C, int M, int N, int K) {
  __shared__ u16 Asl[4][8192];
  __shared__ u16 Bsl[4][8192];
  const int tid = threadIdx.x, lane = tid & 63, w = tid >> 6;
  const int wr = w >> 2, wc = w & 3;
  const int a15 = lane & 15, g4 = lane >> 4;
  const int nbn = N >> 8;
  const int nwg = gridDim.x, bid = blockIdx.x, cpx = nwg >> 3;
  const int swz = (bid & 7) * cpx + (bid >> 3);
  const int bm = swz / nbn, bn = swz % nbn;
  const int Ar0 = bm * 256, Br0 = bn * 256;

  const int rowoff = w * 32 + (lane >> 2);
  const int colswz = ((lane & 3) ^ ((lane >> 3) & 3)) * 8;
  const u16* Agl = A + (size_t)(Ar0 + rowoff) * K + colswz;
  const u16* Bgl = Bm + (size_t)(Br0 + rowoff) * K + colswz;
  const int lb = w * 1024;

  const int rdc = (((lane >> 4) ^ ((lane >> 1) & 3))) * 8;
  const int arow = wr * 128 + a15;
  const int brow = wc * 64 + a15;

  f32x4 acc[8][4];
#pragma unroll
  for (int m = 0; m < 8; m++)
#pragma unroll
    for (int n = 0; n < 4; n++) acc[m][n] = (f32x4){0.f, 0.f, 0.f, 0.f};

  auto STA = [&](int ktile, int kk, int slot) {
    const u16* g = Agl + ktile * 64 + kk * 32;
    gload_lds16(g, &Asl[slot][lb]);
    gload_lds16(g + (size_t)16 * K, &Asl[slot][lb + 512]);
  };
  auto STB = [&](int ktile, int kk, int slot) {
    const u16* g = Bgl + ktile * 64 + kk * 32;
    gload_lds16(g, &Bsl[slot][lb]);
    gload_lds16(g + (size_t)16 * K, &Bsl[slot][lb + 512]);
  };
  auto LOADF = [&](int P, int kk, bf16x8 (&af)[8], bf16x8 (&bv)[4]) {
    const u16* As_ = Asl[P * 2 + kk];
    const u16* Bs_ = Bsl[P * 2 + kk];
#pragma unroll
    for (int mf = 0; mf < 8; mf++)
      af[mf] = __builtin_bit_cast(
          bf16x8, *reinterpret_cast<const ushort8v*>(&As_[(arow + mf * 16) * 32 + rdc]));
#pragma unroll
    for (int nf = 0; nf < 4; nf++)
      bv[nf] = __builtin_bit_cast(
          bf16x8, *reinterpret_cast<const ushort8v*>(&Bs_[(brow + nf * 16) * 32 + rdc]));
  };
  auto MM = [&](bf16x8 (&af)[8], bf16x8 (&bv)[4]) {
    __builtin_amdgcn_s_setprio(1);
#pragma unroll
    for (int mf = 0; mf < 8; mf++)
#pragma unroll
      for (int nf = 0; nf < 4; nf++)
        acc[mf][nf] =
            __builtin_amdgcn_mfma_f32_16x16x32_bf16(af[mf], bv[nf], acc[mf][nf], 0, 0, 0);
    __builtin_amdgcn_s_setprio(0);
  };
  // staggered phase: even waves compute first (LDS pipe free for odd waves'
  // reads), odd waves read first (matrix pipe free for even waves' MFMAs)
  auto PH2 = [&](int P, int kk, bf16x8 (&lA)[8], bf16x8 (&lB)[4],
                 bf16x8 (&mA)[8], bf16x8 (&mB)[4]) {
    if (w & 1) {
      LOADF(P, kk, lA, lB);
      MM(mA, mB);
    } else {
      MM(mA, mB);
      LOADF(P, kk, lA, lB);
    }
  };

  bf16x8 f0A[8], f1A[8];
  bf16x8 f0B[4], f1B[4];

  const int NT = K >> 6;
  STA(0, 0, 0); STB(0, 0, 0);
  STA(0, 1, 1); STB(0, 1, 1);
  STA(1, 0, 2); STB(1, 0, 2);
  VM8;
  BARR;
  LOADF(0, 0, f0A, f0B);

  for (int T = 0; T + 2 < NT; ++T) {
    int P = T & 1, Q = P ^ 1;
    STA(T + 1, 1, Q * 2 + 1); STB(T + 1, 1, Q * 2 + 1);
    VM10; BARR; SCB;
    PH2(P, 1, f1A, f1B, f0A, f0B);
    BARR;
    STA(T + 2, 0, P * 2 + 0); STB(T + 2, 0, P * 2 + 0);
    VM10; BARR; SCB;
    PH2(Q, 0, f0A, f0B, f1A, f1B);
    BARR;
  }
  {
    int T = NT - 2, P = T & 1, Q = P ^ 1;
    STA(T + 1, 1, Q * 2 + 1); STB(T + 1, 1, Q * 2 + 1);
    VM10; BARR; SCB;
    PH2(P, 1, f1A, f1B, f0A, f0B);
    BARR;
    VM8; BARR; SCB;
    PH2(Q, 0, f0A, f0B, f1A, f1B);
    BARR;
  }
  {
    int P = (NT - 1) & 1;
    VM0; BARR; SCB;
    PH2(P, 1, f1A, f1B, f0A, f0B);
    LGKM0;
    BARR;
    MM(f1A, f1B);
  }

  if constexpr (sizeof(OT) == 2) {
    // wave-private 16KB region; col XOR (g4<<4) -> 2-way banks (free)
    u16* ep = (w < 4) ? Asl[w] : Bsl[w - 4];
#pragma unroll
    for (int mfg = 0; mfg < 8; mfg++)
#pragma unroll
      for (int q = 0; q < 4; q++)
#pragma unroll
        for (int nf = 0; nf < 4; nf++)
          ep[(mfg * 16 + g4 * 4 + q) * 64 + ((nf * 16 + a15) ^ (g4 << 4))] =
              f2bf(acc[mfg][nf][q]);
    OT* cbase = C + (size_t)(Ar0 + wr * 128) * N + Br0 + wc * 64;
#pragma unroll
    for (int i = 0; i < 16; i++) {
      int id = lane + 64 * i;
      int row = id >> 3, k16 = id & 7;
      int pc = (k16 * 8) ^ (((row >> 2) & 3) << 4);
      ushort8v v8 = *reinterpret_cast<const ushort8v*>(&ep[row * 64 + pc]);
      *reinterpret_cast<ushort8v*>(cbase + (size_t)row * N + k16 * 8) = v8;
    }
  } else {
    // fp32: two 16KB halves (64x64 f32), same XOR swizzle, coalesced dwordx4
    float* epf = reinterpret_cast<float*>((w < 4) ? Asl[w] : Bsl[w - 4]);
#pragma unroll
    for (int half = 0; half < 2; half++) {
#pragma unroll
      for (int mm = 0; mm < 4; mm++) {
        int mfg = half * 4 + mm;
#pragma unroll
        for (int q = 0; q < 4; q++)
#pragma unroll
          for (int nf = 0; nf < 4; nf++)
            epf[(mm * 16 + g4 * 4 + q) * 64 + ((nf * 16 + a15) ^ (g4 << 4))] =
                acc[mfg][nf][q];
      }
      OT* cbase = C + (size_t)(Ar0 + wr * 128 + half * 64) * N + Br0 + wc * 64;
#pragma unroll
      for (int i = 0; i < 16; i++) {
        int id = lane + 64 * i;
        int row = id >> 4, c4 = id & 15;
        int pc = (c4 * 4) ^ (((row >> 2) & 3) << 4);
        float4 v = *reinterpret_cast<const float4*>(&epf[row * 64 + pc]);
        *reinterpret_cast<float4*>(cbase + (size_t)row * N + c4 * 4) = v;
      }
      if (half == 0) { LGKM0; }
    }
  }
}

// ---------------- scan phase 1 (MFMA, 1-wave blocks) ----------------
template <int CHL>
__global__ __launch_bounds__(64) void scan_phase1_mfma(
    const u16* __restrict__ Kb, const u16* __restrict__ Vb,
    const float* __restrict__ td, float* __restrict__ chunks) {
  constexpr int NCH = T_ / CHL;
  constexpr int LDW = CHL + 8;
  __shared__ u16 Ash[64 * LDW];
  __shared__ u16 Vsh[64 * LDW];
  int lane = threadIdx.x & 63;
  int gw = blockIdx.x;
  int c = gw & (NCH - 1), bh = gw / NCH;
  int h = bh & 31, b = bh >> 5;

  size_t base = ((size_t)b * T_ + (size_t)c * CHL) * C_ + h * 64 + lane;
  const u16* Kp = Kb + base;
  const u16* Vp = Vb + base;

  {
    float w = __expf(-__expf(td[h * 64 + lane]));
    u16* Arow = &Ash[lane * LDW];
    float p = 1.f;
#pragma unroll
    for (int i4 = CHL - 4; i4 >= 0; i4 -= 4) {
      float a3 = bf2f(Kp[(size_t)(i4 + 3) * C_]) * p; p *= w;
      float a2 = bf2f(Kp[(size_t)(i4 + 2) * C_]) * p; p *= w;
      float a1 = bf2f(Kp[(size_t)(i4 + 1) * C_]) * p; p *= w;
      float a0 = bf2f(Kp[(size_t)(i4 + 0) * C_]) * p; p *= w;
      ushort4 pk;
      pk.x = f2bf(a0); pk.y = f2bf(a1); pk.z = f2bf(a2); pk.w = f2bf(a3);
      *reinterpret_cast<ushort4*>(&Arow[i4]) = pk;
    }
  }
  {
    u16* Vrow = &Vsh[lane * LDW];
#pragma unroll
    for (int i4 = 0; i4 < CHL; i4 += 4) {
      ushort4 pk;
      pk.x = Vp[(size_t)(i4 + 0) * C_];
      pk.y = Vp[(size_t)(i4 + 1) * C_];
      pk.z = Vp[(size_t)(i4 + 2) * C_];
      pk.w = Vp[(size_t)(i4 + 3) * C_];
      *reinterpret_cast<ushort4*>(&Vrow[i4]) = pk;
    }
  }

  f32x4 acc[4][4];
#pragma unroll
  for (int m = 0; m < 4; m++)
#pragma unroll
    for (int n = 0; n < 4; n++) acc[m][n] = (f32x4){0.f, 0.f, 0.f, 0.f};

#pragma unroll
  for (int kb = 0; kb < CHL / 32; kb++) {
    int ko = kb * 32 + (lane >> 4) * 8;
    bf16x8 Af[4], Bf[4];
#pragma unroll
    for (int m = 0; m < 4; m++) {
      ushort8v t8 = *reinterpret_cast<const ushort8v*>(&Ash[(m * 16 + (lane & 15)) * LDW + ko]);
      Af[m] = __builtin_bit_cast(bf16x8, t8);
    }
#pragma unroll
    for (int n = 0; n < 4; n++) {
      ushort8v t8 = *reinterpret_cast<const ushort8v*>(&Vsh[(n * 16 + (lane & 15)) * LDW + ko]);
      Bf[n] = __builtin_bit_cast(bf16x8, t8);
    }
#pragma unroll
    for (int m = 0; m < 4; m++)
#pragma unroll
      for (int n = 0; n < 4; n++)
        acc[m][n] = __builtin_amdgcn_mfma_f32_16x16x32_bf16(Af[m], Bf[n], acc[m][n], 0, 0, 0);
  }

  float* outp = chunks + (((size_t)c * B_ + b) * H_ + h) * 4096;
  int r0 = (lane >> 4) * 4, c0 = lane & 15;
#pragma unroll
  for (int m = 0; m < 4; m++)
#pragma unroll
    for (int n = 0; n < 4; n++)
#pragma unroll
      for (int q = 0; q < 4; q++)
        outp[(size_t)(m * 16 + r0 + q) * 64 + n * 16 + c0] = acc[m][n][q];
}

// ---------------- scan phase 1 (scalar fallback) ----------------
template <int NCH, int CHL>
__global__ __launch_bounds__(256) void scan_phase1(
    const u16* __restrict__ Kb, const u16* __restrict__ Vb,
    const float* __restrict__ td, float* __restrict__ chunks) {
  int lane = threadIdx.x & 63;
  int gw = (blockIdx.x * 256 + threadIdx.x) >> 6;
  int c = gw & (NCH - 1), bh = gw / NCH;
  int h = bh & 31, b = bh >> 5;
  const float* tdh = td + h * 64;
  float wreg[64];
#pragma unroll
  for (int s = 0; s < 64; s++) wreg[s] = __expf(-__expf(tdh[s]));
  float st[64];
#pragma unroll
  for (int s = 0; s < 64; s++) st[s] = 0.f;
  size_t base = ((size_t)b * T_ + (size_t)c * CHL) * C_ + h * 64 + lane;
  const u16* Kp = Kb + base;
  const u16* Vp = Vb + base;
  for (int t = 0; t < CHL; t++) {
    float kcur = bf2f(Kp[(size_t)t * C_]), vcur = bf2f(Vp[(size_t)t * C_]);
#pragma unroll
    for (int s = 0; s < 64; s++) {
      float ks = __shfl(kcur, s);
      st[s] = fmaf(wreg[s], st[s], ks * vcur);
    }
  }
  float* outp = chunks + (((size_t)c * B_ + b) * H_ + h) * 4096 + lane;
#pragma unroll
  for (int s = 0; s < 64; s++) outp[s * 64] = st[s];
}

// ---------------- scan phase 2 ----------------
template <int NCH, int CHL>
__global__ __launch_bounds__(256) void scan_phase2(
    const float* __restrict__ st0, const float* __restrict__ td,
    float* __restrict__ chunks, float* __restrict__ state_out) {
  int idx = blockIdx.x * 256 + threadIdx.x;
  int h = (idx >> 12) & 31;
  int s = (idx >> 6) & 63;
  float wL = __expf(-(float)CHL * __expf(td[h * 64 + s]));
  float st = st0[idx];
#pragma unroll
  for (int cc = 0; cc < NCH; cc++) {
    size_t off = (size_t)cc * 524288 + idx;
    float sc = chunks[off];
    chunks[off] = st;
    st = fmaf(wL, st, sc);
  }
  state_out[idx] = st;
}

// ---------------- scan phase 3 (MFMA, 4-wave blocks, CHL=64) ----------------
__global__ __launch_bounds__(256) void scan_phase3_mfma(
    const u16* __restrict__ Rb, const u16* __restrict__ Kb,
    const u16* __restrict__ Vb, const float* __restrict__ td,
    const float* __restrict__ tf, const float* __restrict__ chunks,
    const u16* __restrict__ Gb, const float* __restrict__ lnw,
    const float* __restrict__ lnb, u16* __restrict__ Y) {
  __shared__ __align__(16) u16 smem[4][5248];
  int lane = threadIdx.x & 63, wib = threadIdx.x >> 6;
  int gw = blockIdx.x * 4 + wib;
  int c = gw & 31, bh = gw >> 5;
  int h = bh & 31, b = bh >> 5;
  int a = lane & 15, g = lane >> 4;
  int h0 = h * 64;

  u16* Kt = smem[wib];
  u16* Vt = Kt + 1024;
  u16* StT = Vt + 1024;
  u16* AT = StT + 2560;

  f32x8 sA[2], sB[2], sC[2], uA[2];
#pragma unroll
  for (int kk = 0; kk < 2; kk++) {
#pragma unroll
    for (int e = 0; e < 8; e++) {
      int s = kk * 32 + g * 8 + e;
      float ew = __expf(td[h0 + s]);
      sA[kk][e] = __expf(-(float)a * ew);
      sB[kk][e] = __expf(-((float)a - 8.f) * ew);
      sC[kk][e] = __expf(-(7.f - (float)a) * ew);
      uA[kk][e] = tf[h0 + s];
    }
  }
  f32x4 sE[4];
  f32x4 ewD;
#pragma unroll
  for (int ms = 0; ms < 4; ms++) {
    ewD[ms] = __expf(td[h0 + ms * 16 + a]);
#pragma unroll
    for (int q = 0; q < 4; q++)
      sE[ms][q] = __expf(-16.f * __expf(td[h0 + ms * 16 + g * 4 + q]));
  }
  float lwv[4], lbv[4];
#pragma unroll
  for (int nd = 0; nd < 4; nd++) {
    lwv[nd] = lnw[h0 + nd * 16 + a];
    lbv[nd] = lnb[h0 + nd * 16 + a];
  }

  f32x4 St[4][4];
  const float* cpc = chunks + (((size_t)c * B_ + b) * H_ + h) * 4096;
#pragma unroll
  for (int ms = 0; ms < 4; ms++)
#pragma unroll
    for (int nd = 0; nd < 4; nd++)
#pragma unroll
      for (int q = 0; q < 4; q++)
        St[ms][nd][q] = cpc[(size_t)(ms * 16 + g * 4 + q) * 64 + nd * 16 + a];

#pragma unroll
  for (int z = 0; z < 6; z++) {
    int idx = z * 64 + lane;
    int row = idx / 24, col = 16 + idx % 24;
    AT[row * 40 + col] = 0;
  }

  size_t tbase = ((size_t)b * T_ + (size_t)c * 64) * C_ + h0;

  for (int sb = 0; sb < 4; sb++) {
    size_t rb0 = tbase + (size_t)(sb * 16) * C_;

    ushort8v r8[2], k8[2];
#pragma unroll
    for (int kk = 0; kk < 2; kk++) {
      r8[kk] = *reinterpret_cast<const ushort8v*>(Rb + rb0 + (size_t)a * C_ + kk * 32 + g * 8);
      k8[kk] = *reinterpret_cast<const ushort8v*>(Kb + rb0 + (size_t)a * C_ + kk * 32 + g * 8);
    }
    {
      int srow = lane >> 3;
      int scol = (lane & 7) * 8;
      *reinterpret_cast<ushort8v*>(&Kt[srow * 64 + scol]) =
          *reinterpret_cast<const ushort8v*>(Kb + rb0 + (size_t)srow * C_ + scol);
      *reinterpret_cast<ushort8v*>(&Kt[(srow + 8) * 64 + scol]) =
          *reinterpret_cast<const ushort8v*>(Kb + rb0 + (size_t)(srow + 8) * C_ + scol);
      *reinterpret_cast<ushort8v*>(&Vt[srow * 64 + scol]) =
          *reinterpret_cast<const ushort8v*>(Vb + rb0 + (size_t)srow * C_ + scol);
      *reinterpret_cast<ushort8v*>(&Vt[(srow + 8) * 64 + scol]) =
          *reinterpret_cast<const ushort8v*>(Vb + rb0 + (size_t)(srow + 8) * C_ + scol);
    }

    f32x4 O[4];
#pragma unroll
    for (int nd = 0; nd < 4; nd++) O[nd] = (f32x4){0.f, 0.f, 0.f, 0.f};

#pragma unroll
    for (int kk = 0; kk < 2; kk++) {
#pragma unroll
      for (int msl = 0; msl < 2; msl++) {
        int ms = kk * 2 + msl;
#pragma unroll
        for (int nd = 0; nd < 4; nd++) {
          ushort4 pk;
          pk.x = f2bf(St[ms][nd][0]); pk.y = f2bf(St[ms][nd][1]);
          pk.z = f2bf(St[ms][nd][2]); pk.w = f2bf(St[ms][nd][3]);
          *reinterpret_cast<ushort4*>(&StT[(a + nd * 16) * 40 + msl * 16 + g * 4]) = pk;
        }
      }
      ushort8v rt;
#pragma unroll
      for (int e = 0; e < 8; e++) rt[e] = f2bf(bf2f(r8[kk][e]) * sA[kk][e]);
      bf16x8 rtf = __builtin_bit_cast(bf16x8, rt);
#pragma unroll
      for (int nd = 0; nd < 4; nd++) {
        ushort8v sfr = *reinterpret_cast<const ushort8v*>(&StT[(a + nd * 16) * 40 + g * 8]);
        O[nd] = __builtin_amdgcn_mfma_f32_16x16x32_bf16(
            rtf, __builtin_bit_cast(bf16x8, sfr), O[nd], 0, 0, 0);
      }
    }

    float p = 0.f;
#pragma unroll
    for (int kk = 0; kk < 2; kk++)
#pragma unroll
      for (int e = 0; e < 8; e++)
        p = fmaf(bf2f(r8[kk][e]) * uA[kk][e], bf2f(k8[kk][e]), p);
    p += __shfl_xor(p, 16);
    p += __shfl_xor(p, 32);

    f32x4 Am = (f32x4){0.f, 0.f, 0.f, 0.f};
#pragma unroll
    for (int kk = 0; kk < 2; kk++) {
      ushort8v kh, rh;
#pragma unroll
      for (int e = 0; e < 8; e++) {
        kh[e] = f2bf(bf2f(k8[kk][e]) * sC[kk][e]);
        rh[e] = f2bf(bf2f(r8[kk][e]) * sB[kk][e]);
      }
      Am = __builtin_amdgcn_mfma_f32_16x16x32_bf16(
          __builtin_bit_cast(bf16x8, kh), __builtin_bit_cast(bf16x8, rh), Am, 0, 0, 0);
    }
    {
      ushort4 aw;
#pragma unroll
      for (int q = 0; q < 4; q++) {
        int jr = g * 4 + q;
        float v = (jr < a) ? Am[q] : ((jr == a) ? p : 0.f);
        ((u16*)&aw)[q] = f2bf(v);
      }
      *reinterpret_cast<ushort4*>(&AT[a * 40 + g * 4]) = aw;
    }
    bf16x8 afrag;
    {
      ushort8v t8 = *reinterpret_cast<const ushort8v*>(&AT[a * 40 + g * 8]);
      afrag = __builtin_bit_cast(bf16x8, t8);
    }

    bf16x8 vfrag[4];
#pragma unroll
    for (int nd = 0; nd < 4; nd++) {
      ushort8v t8;
      if (g < 2) {
#pragma unroll
        for (int e = 0; e < 8; e++) t8[e] = Vt[(g * 8 + e) * 64 + a + nd * 16];
      } else {
#pragma unroll
        for (int e = 0; e < 8; e++) t8[e] = 0;
      }
      vfrag[nd] = __builtin_bit_cast(bf16x8, t8);
    }

#pragma unroll
    for (int nd = 0; nd < 4; nd++)
      O[nd] = __builtin_amdgcn_mfma_f32_16x16x32_bf16(afrag, vfrag[nd], O[nd], 0, 0, 0);

#pragma unroll
    for (int ms = 0; ms < 4; ms++)
#pragma unroll
      for (int nd = 0; nd < 4; nd++)
#pragma unroll
        for (int q = 0; q < 4; q++) St[ms][nd][q] *= sE[ms][q];

#pragma unroll
    for (int ms = 0; ms < 4; ms++) {
      ushort8v kt8;
      if (g < 2) {
#pragma unroll
        for (int e = 0; e < 8; e++) {
          int j = g * 8 + e;
          float f = bf2f(Kt[j * 64 + ms * 16 + a]) * __expf(-(15.f - (float)j) * ewD[ms]);
          kt8[e] = f2bf(f);
        }
      } else {
#pragma unroll
        for (int e = 0; e < 8; e++) kt8[e] = 0;
      }
      bf16x8 kf = __builtin_bit_cast(bf16x8, kt8);
#pragma unroll
      for (int nd = 0; nd < 4; nd++)
        St[ms][nd] = __builtin_amdgcn_mfma_f32_16x16x32_bf16(kf, vfrag[nd], St[ms][nd], 0, 0, 0);
    }

#pragma unroll
    for (int nd = 0; nd < 4; nd++)
#pragma unroll
      for (int q = 0; q < 4; q++) O[nd][q] *= 0.125f;
#pragma unroll
    for (int q = 0; q < 4; q++) {
      float ssum = O[0][q] + O[1][q] + O[2][q] + O[3][q];
      ssum += __shfl_xor(ssum, 1); ssum += __shfl_xor(ssum, 2);
      ssum += __shfl_xor(ssum, 4); ssum += __shfl_xor(ssum, 8);
      float mean = ssum * (1.f / 64.f);
      float vv = 0.f;
#pragma unroll
      for (int nd = 0; nd < 4; nd++) {
        float d = O[nd][q] - mean;
        vv = fmaf(d, d, vv);
      }
      vv += __shfl_xor(vv, 1); vv += __shfl_xor(vv, 2);
      vv += __shfl_xor(vv, 4); vv += __shfl_xor(vv, 8);
      float rs = rsqrtf(vv * (1.f / 64.f) + 1e-5f);
      size_t rowoff = rb0 + (size_t)(g * 4 + q) * C_;
#pragma unroll
      for (int nd = 0; nd < 4; nd++) {
        float xn = (O[nd][q] - mean) * rs;
        float gv = bf2f(Gb[rowoff + nd * 16 + a]);
        float sg = gv / (1.f + __expf(-gv));
        Y[rowoff + nd * 16 + a] = f2bf((xn * lwv[nd] + lbv[nd]) * sg);
      }
    }
  }
}

// ---------------- scan phase 3 (scalar fallback, NCH16) ----------------
template <int NCH, int CHL>
__global__ __launch_bounds__(256) void scan_phase3(
    const u16* __restrict__ Rb, const u16* __restrict__ Kb,
    const u16* __restrict__ Vb, const float* __restrict__ td,
    const float* __restrict__ tf, const float* __restrict__ chunks,
    const u16* __restrict__ Gb, const float* __restrict__ lnw,
    const float* __restrict__ lnb, u16* __restrict__ Y) {
  int lane = threadIdx.x & 63;
  int gw = (blockIdx.x * 256 + threadIdx.x) >> 6;
  int c = gw & (NCH - 1), bh = gw / NCH;
  int h = bh & 31, b = bh >> 5;
  const float* tdh = td + h * 64;
  float wreg[64];
#pragma unroll
  for (int s = 0; s < 64; s++) wreg[s] = __expf(-__expf(tdh[s]));
  float u_own = tf[h * 64 + lane];
  float lw = lnw[h * 64 + lane];
  float lb = lnb[h * 64 + lane];
  float st[64];
  const float* cp = chunks + (((size_t)c * B_ + b) * H_ + h) * 4096 + lane;
#pragma unroll
  for (int s = 0; s < 64; s++) st[s] = cp[s * 64];
  size_t base = ((size_t)b * T_ + (size_t)c * CHL) * C_ + h * 64 + lane;
  const u16* Rp = Rb + base;
  const u16* Kp = Kb + base;
  const u16* Vp = Vb + base;
  const u16* Gp = Gb + base;
  u16* Yp = Y + base;
  for (int t = 0; t < CHL; t++) {
    float rcur = bf2f(Rp[(size_t)t * C_]);
    float kcur = bf2f(Kp[(size_t)t * C_]);
    float vcur = bf2f(Vp[(size_t)t * C_]);
    float p = rcur * u_own * kcur;
#pragma unroll
    for (int off = 32; off >= 1; off >>= 1) p += __shfl_xor(p, off);
    float acc = 0.f;
#pragma unroll
    for (int s = 0; s < 64; s++) {
      float rs = __shfl(rcur, s);
      float ks = __shfl(kcur, s);
      acc = fmaf(rs, st[s], acc);
      st[s] = fmaf(wreg[s], st[s], ks * vcur);
    }
    float o = fmaf(p, vcur, acc);
    float x = o * 0.125f;
    float sum = x;
#pragma unroll
    for (int off = 32; off >= 1; off >>= 1) sum += __shfl_xor(sum, off);
    float mean = sum * (1.f / 64.f);
    float d = x - mean;
    float v2 = d * d;
#pragma unroll
    for (int off = 32; off >= 1; off >>= 1) v2 += __shfl_xor(v2, off);
    float var = v2 * (1.f / 64.f);
    float xn = d * rsqrtf(var + 1e-5f);
    float gg = bf2f(Gp[(size_t)t * C_]);
    float sg = gg / (1.f + __expf(-gg));
    Yp[(size_t)t * C_] = f2bf((xn * lw + lb) * sg);
  }
}

extern "C" void kernel_launch(void* const* d_in, const int* in_sizes, int n_in,
                              void* d_out, int out_size, void* d_ws, size_t ws_size,
                              hipStream_t stream) {
  const float* hidden = (const float*)d_in[0];
  const float* state0 = (const float*)d_in[1];
  const float* td = (const float*)d_in[2];
  const float* tf = (const float*)d_in[3];
  const float* mk = (const float*)d_in[4];
  const float* mv = (const float*)d_in[5];
  const float* mr = (const float*)d_in[6];
  const float* mg = (const float*)d_in[7];
  const float* kw = (const float*)d_in[8];
  const float* vw = (const float*)d_in[9];
  const float* rw = (const float*)d_in[10];
  const float* gw = (const float*)d_in[11];
  const float* ow = (const float*)d_in[12];
  const float* lnw = (const float*)d_in[13];
  const float* lnb = (const float*)d_in[14];

  float* out = (float*)d_out;
  float* state_f = out + (size_t)B_ * T_ * C_;

  const size_t BUF = (size_t)B_ * T_ * C_ * 2;       // 33,554,432 B
  const size_t WBUF = (size_t)C_ * C_ * 2;           // 8,388,608 B
  const size_t needOpt = 7 * BUF + WBUF;             // 243,269,632 B

  dim3 blk(256);
  int mixGrid = (B_ * T_ * C_ / 4) / 256;
  int convN4 = C_ * C_ / 4;
  int convGrid = convN4 / 256;
  int gemmGrid = (B_ * T_ / 256) * (C_ / 256);
  dim3 gblk(512);

  if (ws_size >= needOpt) {
    char* base = (char*)d_ws;
    u16* mixG = (u16*)(base + 0 * BUF);          // A
    u16* mixR = (u16*)(base + 1 * BUF);          // B
    u16* mixK = (u16*)(base + 2 * BUF);          // C
    u16* mixV = (u16*)(base + 3 * BUF);          // D
    u16* wb   = (u16*)(base + 4 * BUF);
    u16* gb   = (u16*)(base + 4 * BUF + WBUF);
    u16* kb   = (u16*)(base + 5 * BUF + WBUF);
    u16* vb   = (u16*)(base + 6 * BUF + WBUF);
    u16* rb   = mixG;                            // alias A (dead after G-gemm)
    u16* Y    = mixR;                            // alias B (dead after R-gemm)
    float* chunks = (float*)(base + 2 * BUF);    // alias C+D (dead after K,V-gemms)

    mix4p_cast_kernel<<<B_ * T_, blk, 0, stream>>>(hidden, mk, mv, mr, mg,
                                                   mixK, mixV, mixR, mixG);
    conv_bf16_kernel<<<convGrid, blk, 0, stream>>>(gw, wb, convN4);
    gemm_bt256<u16><<<gemmGrid, gblk, 0, stream>>>(mixG, wb, gb, B_ * T_, C_, C_);
    conv_bf16_kernel<<<convGrid, blk, 0, stream>>>(rw, wb, convN4);
    gemm_bt256<u16><<<gemmGrid, gblk, 0, stream>>>(mixR, wb, rb, B_ * T_, C_, C_);
    conv_bf16_kernel<<<convGrid, blk, 0, stream>>>(kw, wb, convN4);
    gemm_bt256<u16><<<gemmGrid, gblk, 0, stream>>>(mixK, wb, kb, B_ * T_, C_, C_);
    conv_bf16_kernel<<<convGrid, blk, 0, stream>>>(vw, wb, convN4);
    gemm_bt256<u16><<<gemmGrid, gblk, 0, stream>>>(mixV, wb, vb, B_ * T_, C_, C_);

    scan_phase1_mfma<64><<<B_ * H_ * 32, dim3(64), 0, stream>>>(kb, vb, td, chunks);
    scan_phase2<32, 64><<<2048, blk, 0, stream>>>(state0, td, chunks, state_f);
    scan_phase3_mfma<<<(B_ * H_ * 32) / 4, blk, 0, stream>>>(rb, kb, vb, td, tf, chunks, gb, lnw, lnb, Y);

    conv_bf16_kernel<<<convGrid, blk, 0, stream>>>(ow, wb, convN4);
    gemm_bt256<float><<<gemmGrid, gblk, 0, stream>>>(Y, wb, out, B_ * T_, C_, C_);
    return;
  }

  // minimal fallback (~209.7 MB): NCH16 scalar scans, serialized mixes
  char* ws = (char*)d_ws;
  u16* mixA = (u16*)ws;    ws += BUF;
  u16* wb = (u16*)ws;      ws += WBUF;
  u16* rb = (u16*)ws;      ws += BUF;
  u16* kb = (u16*)ws;      ws += BUF;
  u16* vb = (u16*)ws;      ws += BUF;
  u16* gb = (u16*)ws;      ws += BUF;
  float* chunks = (float*)ws;

  mix_cast_kernel<<<mixGrid, blk, 0, stream>>>(hidden, mr, mixA);
  conv_bf16_kernel<<<convGrid, blk, 0, stream>>>(rw, wb, convN4);
  gemm_bt256<u16><<<gemmGrid, gblk, 0, stream>>>(mixA, wb, rb, B_ * T_, C_, C_);
  mix_cast_kernel<<<mixGrid, blk, 0, stream>>>(hidden, mk, mixA);
  conv_bf16_kernel<<<convGrid, blk, 0, stream>>>(kw, wb, convN4);
  gemm_bt256<u16><<<gemmGrid, gblk, 0, stream>>>(mixA, wb, kb, B_ * T_, C_, C_);
  mix_cast_kernel<<<mixGrid, blk, 0, stream>>>(hidden, mv, mixA);
  conv_bf16_kernel<<<convGrid, blk, 0, stream>>>(vw, wb, convN4);
  gemm_bt256<u16><<<gemmGrid, gblk, 0, stream>>>(mixA, wb, vb, B_ * T_, C_, C_);
  mix_cast_kernel<<<mixGrid, blk, 0, stream>>>(hidden, mg, mixA);
  conv_bf16_kernel<<<convGrid, blk, 0, stream>>>(gw, wb, convN4);
  gemm_bt256<u16><<<gemmGrid, gblk, 0, stream>>>(mixA, wb, gb, B_ * T_, C_, C_);

  scan_phase1<16, 128><<<(B_ * H_ * 16) / 4, blk, 0, stream>>>(kb, vb, td, chunks);
  scan_phase2<16, 128><<<2048, blk, 0, stream>>>(state0, td, chunks, state_f);
  scan_phase3<16, 128><<<(B_ * H_ * 16) / 4, blk, 0, stream>>>(rb, kb, vb, td, tf, chunks, gb, lnw, lnb, mixA);

  conv_bf16_kernel<<<convGrid, blk, 0, stream>>>(ow, wb, convN4);
  gemm_bt256<float><<<gemmGrid, gblk, 0, stream>>>(mixA, wb, out, B_ * T_, C_, C_);
}

// Round 23
// 610.879 us; speedup vs baseline: 8.0533x; 8.0533x over previous
//
#include <hip/hip_runtime.h>
#include <hip/hip_bf16.h>

typedef unsigned short u16;
typedef __bf16 bf16x8 __attribute__((ext_vector_type(8)));
typedef unsigned short ushort8v __attribute__((ext_vector_type(8)));
typedef float f32x4 __attribute__((ext_vector_type(4)));
typedef float f32x8 __attribute__((ext_vector_type(8)));

#define B_ 4
#define T_ 2048
#define C_ 2048
#define H_ 32
#define S_ 64

__device__ __forceinline__ u16 f2bf(float x) {
  __bf16 b = (__bf16)x;  // native RNE conversion
  return __builtin_bit_cast(u16, b);
}
__device__ __forceinline__ float bf2f(u16 x) {
  return __uint_as_float(((unsigned int)x) << 16);
}
__device__ __forceinline__ void gload_lds16(const void* g, void* l) {
  __builtin_amdgcn_global_load_lds(
      (const __attribute__((address_space(1))) void*)g,
      (__attribute__((address_space(3))) void*)l, 16, 0, 0);
}

#define VM10 asm volatile("s_waitcnt vmcnt(10)" ::: "memory")
#define VM8 asm volatile("s_waitcnt vmcnt(8)" ::: "memory")
#define VM0 asm volatile("s_waitcnt vmcnt(0)" ::: "memory")
#define LGKM0 asm volatile("s_waitcnt lgkmcnt(0)" ::: "memory")
#define BARR __builtin_amdgcn_s_barrier()
#define SCB __builtin_amdgcn_sched_barrier(0)

// ---------------- single mix + cast to bf16 (fallback path) ----------------
__global__ __launch_bounds__(256) void mix_cast_kernel(
    const float* __restrict__ hidden, const float* __restrict__ mixp,
    u16* __restrict__ out) {
  int idx = blockIdx.x * 256 + threadIdx.x;
  int c4 = idx & 511;
  int bt = idx >> 9;
  int t = bt & (T_ - 1);
  float4 h = reinterpret_cast<const float4*>(hidden)[idx];
  float4 m = reinterpret_cast<const float4*>(mixp)[c4];
  float4 sh = make_float4(0.f, 0.f, 0.f, 0.f);
  if (t != 0) sh = reinterpret_cast<const float4*>(hidden)[idx - 512];
  ushort4 o;
  o.x = f2bf(h.x * m.x + sh.x * (1.f - m.x));
  o.y = f2bf(h.y * m.y + sh.y * (1.f - m.y));
  o.z = f2bf(h.z * m.z + sh.z * (1.f - m.z));
  o.w = f2bf(h.w * m.w + sh.w * (1.f - m.w));
  reinterpret_cast<ushort4*>(out)[idx] = o;
}

// ---------------- fused 4-way mix + cast, row-paired (1.5 reads/row) ----------------
__global__ __launch_bounds__(256) void mix4p_cast_kernel(
    const float* __restrict__ hidden,
    const float* __restrict__ mK, const float* __restrict__ mV,
    const float* __restrict__ mR, const float* __restrict__ mG,
    u16* __restrict__ oK, u16* __restrict__ oV,
    u16* __restrict__ oR, u16* __restrict__ oG) {
  int bid = blockIdx.x;            // 8192 = (B*T/2) * 2 col-halves
  int colh = bid & 1;
  int rp = bid >> 1;               // row pair index
  int c4 = colh * 256 + threadIdx.x;   // 0..511
  int bt0 = rp * 2;
  int t0 = bt0 & (T_ - 1);
  size_t i0 = (size_t)bt0 * 512 + c4;
  float4 h0 = reinterpret_cast<const float4*>(hidden)[i0];
  float4 h1 = reinterpret_cast<const float4*>(hidden)[i0 + 512];
  float4 hp = make_float4(0.f, 0.f, 0.f, 0.f);
  if (t0 != 0) hp = reinterpret_cast<const float4*>(hidden)[i0 - 512];
  float4 m;
  ushort4 o0, o1;
#define DOMIX2(MP, OP)                                           \
  m = reinterpret_cast<const float4*>(MP)[c4];                   \
  o0.x = f2bf(h0.x * m.x + hp.x * (1.f - m.x));                  \
  o0.y = f2bf(h0.y * m.y + hp.y * (1.f - m.y));                  \
  o0.z = f2bf(h0.z * m.z + hp.z * (1.f - m.z));                  \
  o0.w = f2bf(h0.w * m.w + hp.w * (1.f - m.w));                  \
  o1.x = f2bf(h1.x * m.x + h0.x * (1.f - m.x));                  \
  o1.y = f2bf(h1.y * m.y + h0.y * (1.f - m.y));                  \
  o1.z = f2bf(h1.z * m.z + h0.z * (1.f - m.z));                  \
  o1.w = f2bf(h1.w * m.w + h0.w * (1.f - m.w));                  \
  reinterpret_cast<ushort4*>(OP)[i0] = o0;                       \
  reinterpret_cast<ushort4*>(OP)[i0 + 512] = o1;
  DOMIX2(mK, oK)
  DOMIX2(mV, oV)
  DOMIX2(mR, oR)
  DOMIX2(mG, oG)
#undef DOMIX2
}

// ---------------- fp32 -> bf16 weight cast ----------------
__global__ __launch_bounds__(256) void conv_bf16_kernel(
    const float* __restrict__ in, u16* __restrict__ out, int n4) {
  int i = blockIdx.x * 256 + threadIdx.x;
  if (i >= n4) return;
  float4 v = reinterpret_cast<const float4*>(in)[i];
  ushort4 o;
  o.x = f2bf(v.x); o.y = f2bf(v.y); o.z = f2bf(v.z); o.w = f2bf(v.w);
  reinterpret_cast<ushort4*>(out)[i] = o;
}

// ---------------- 256x256 bf16 GEMM (r15 schedule + fragment prefetch;
// LDS epilogues for both output types, XOR-swizzled) ----------
template <typename OT>
__global__ __launch_bounds__(512, 2) void gemm_bt256(
    const u16* __restrict__ A, const u16* __restrict__ Bm,
    OT* __restrict__ C, int M, int N, int K) {
  __shared__ u16 Asl[4][8192];
  __shared__ u16 Bsl[4][8192];
  const int tid = threadIdx.x, lane = tid & 63, w = tid >> 6;
  const int wr = w >> 2, wc = w & 3;
  const int a15 = lane & 15, g4 = lane >> 4;
  const int nbn = N >> 8;
  const int nwg = gridDim.x, bid = blockIdx.x, cpx = nwg >> 3;
  const int swz = (bid & 7) * cpx + (bid >> 3);
  const int bm = swz / nbn, bn = swz % nbn;
  const int Ar0 = bm * 256, Br0 = bn * 256;

  const int rowoff = w * 32 + (lane >> 2);
  const int colswz = ((lane & 3) ^ ((lane >> 3) & 3)) * 8;
  const u16* Agl = A + (size_t)(Ar0 + rowoff) * K + colswz;
  const u16* Bgl = Bm + (size_t)(Br0 + rowoff) * K + colswz;
  const int lb = w * 1024;

  const int rdc = (((lane >> 4) ^ ((lane >> 1) & 3))) * 8;
  const int arow = wr * 128 + a15;
  const int brow = wc * 64 + a15;

  f32x4 acc[8][4];
#pragma unroll
  for (int m = 0; m < 8; m++)
#pragma unroll
    for (int n = 0; n < 4; n++) acc[m][n] = (f32x4){0.f, 0.f, 0.f, 0.f};

  auto STA = [&](int ktile, int kk, int slot) {
    const u16* g = Agl + ktile * 64 + kk * 32;
    gload_lds16(g, &Asl[slot][lb]);
    gload_lds16(g + (size_t)16 * K, &Asl[slot][lb + 512]);
  };
  auto STB = [&](int ktile, int kk, int slot) {
    const u16* g = Bgl + ktile * 64 + kk * 32;
    gload_lds16(g, &Bsl[slot][lb]);
    gload_lds16(g + (size_t)16 * K, &Bsl[slot][lb + 512]);
  };
  auto LOADF = [&](int P, int kk, bf16x8 (&af)[8], bf16x8 (&bv)[4]) {
    const u16* As_ = Asl[P * 2 + kk];
    const u16* Bs_ = Bsl[P * 2 + kk];
#pragma unroll
    for (int mf = 0; mf < 8; mf++)
      af[mf] = __builtin_bit_cast(
          bf16x8, *reinterpret_cast<const ushort8v*>(&As_[(arow + mf * 16) * 32 + rdc]));
#pragma unroll
    for (int nf = 0; nf < 4; nf++)
      bv[nf] = __builtin_bit_cast(
          bf16x8, *reinterpret_cast<const ushort8v*>(&Bs_[(brow + nf * 16) * 32 + rdc]));
  };
  auto MM = [&](bf16x8 (&af)[8], bf16x8 (&bv)[4]) {
    __builtin_amdgcn_s_setprio(1);
#pragma unroll
    for (int mf = 0; mf < 8; mf++)
#pragma unroll
      for (int nf = 0; nf < 4; nf++)
        acc[mf][nf] =
            __builtin_amdgcn_mfma_f32_16x16x32_bf16(af[mf], bv[nf], acc[mf][nf], 0, 0, 0);
    __builtin_amdgcn_s_setprio(0);
  };

  bf16x8 f0A[8], f1A[8];
  bf16x8 f0B[4], f1B[4];

  const int NT = K >> 6;
  STA(0, 0, 0); STB(0, 0, 0);
  STA(0, 1, 1); STB(0, 1, 1);
  STA(1, 0, 2); STB(1, 0, 2);
  VM8;
  BARR;
  LOADF(0, 0, f0A, f0B);

  for (int T = 0; T + 2 < NT; ++T) {
    int P = T & 1, Q = P ^ 1;
    STA(T + 1, 1, Q * 2 + 1); STB(T + 1, 1, Q * 2 + 1);
    VM10; BARR; SCB;
    LOADF(P, 1, f1A, f1B);
    MM(f0A, f0B);
    BARR;
    STA(T + 2, 0, P * 2 + 0); STB(T + 2, 0, P * 2 + 0);
    VM10; BARR; SCB;
    LOADF(Q, 0, f0A, f0B);
    MM(f1A, f1B);
    BARR;
  }
  {
    int T = NT - 2, P = T & 1, Q = P ^ 1;
    STA(T + 1, 1, Q * 2 + 1); STB(T + 1, 1, Q * 2 + 1);
    VM10; BARR; SCB;
    LOADF(P, 1, f1A, f1B);
    MM(f0A, f0B);
    BARR;
    VM8; BARR; SCB;
    LOADF(Q, 0, f0A, f0B);
    MM(f1A, f1B);
    BARR;
  }
  {
    int P = (NT - 1) & 1;
    VM0; BARR; SCB;
    LOADF(P, 1, f1A, f1B);
    MM(f0A, f0B);
    LGKM0;
    BARR;
    MM(f1A, f1B);
  }

  if constexpr (sizeof(OT) == 2) {
    // wave-private 16KB region; col XOR (g4<<4) -> 2-way banks (free)
    u16* ep = (w < 4) ? Asl[w] : Bsl[w - 4];
#pragma unroll
    for (int mfg = 0; mfg < 8; mfg++)
#pragma unroll
      for (int q = 0; q < 4; q++)
#pragma unroll
        for (int nf = 0; nf < 4; nf++)
          ep[(mfg * 16 + g4 * 4 + q) * 64 + ((nf * 16 + a15) ^ (g4 << 4))] =
              f2bf(acc[mfg][nf][q]);
    OT* cbase = C + (size_t)(Ar0 + wr * 128) * N + Br0 + wc * 64;
#pragma unroll
    for (int i = 0; i < 16; i++) {
      int id = lane + 64 * i;
      int row = id >> 3, k16 = id & 7;
      int pc = (k16 * 8) ^ (((row >> 2) & 3) << 4);
      ushort8v v8 = *reinterpret_cast<const ushort8v*>(&ep[row * 64 + pc]);
      *reinterpret_cast<ushort8v*>(cbase + (size_t)row * N + k16 * 8) = v8;
    }
  } else {
    // fp32: two 16KB halves (64x64 f32), same XOR swizzle, coalesced dwordx4
    float* epf = reinterpret_cast<float*>((w < 4) ? Asl[w] : Bsl[w - 4]);
#pragma unroll
    for (int half = 0; half < 2; half++) {
#pragma unroll
      for (int mm = 0; mm < 4; mm++) {
        int mfg = half * 4 + mm;
#pragma unroll
        for (int q = 0; q < 4; q++)
#pragma unroll
          for (int nf = 0; nf < 4; nf++)
            epf[(mm * 16 + g4 * 4 + q) * 64 + ((nf * 16 + a15) ^ (g4 << 4))] =
                acc[mfg][nf][q];
      }
      OT* cbase = C + (size_t)(Ar0 + wr * 128 + half * 64) * N + Br0 + wc * 64;
#pragma unroll
      for (int i = 0; i < 16; i++) {
        int id = lane + 64 * i;
        int row = id >> 4, c4 = id & 15;
        int pc = (c4 * 4) ^ (((row >> 2) & 3) << 4);
        float4 v = *reinterpret_cast<const float4*>(&epf[row * 64 + pc]);
        *reinterpret_cast<float4*>(cbase + (size_t)row * N + c4 * 4) = v;
      }
      if (half == 0) { LGKM0; }
    }
  }
}

// ---------------- scan phase 1 (MFMA, 1-wave blocks) ----------------
template <int CHL>
__global__ __launch_bounds__(64) void scan_phase1_mfma(
    const u16* __restrict__ Kb, const u16* __restrict__ Vb,
    const float* __restrict__ td, float* __restrict__ chunks) {
  constexpr int NCH = T_ / CHL;
  constexpr int LDW = CHL + 8;
  __shared__ u16 Ash[64 * LDW];
  __shared__ u16 Vsh[64 * LDW];
  int lane = threadIdx.x & 63;
  int gw = blockIdx.x;
  int c = gw & (NCH - 1), bh = gw / NCH;
  int h = bh & 31, b = bh >> 5;

  size_t base = ((size_t)b * T_ + (size_t)c * CHL) * C_ + h * 64 + lane;
  const u16* Kp = Kb + base;
  const u16* Vp = Vb + base;

  {
    float w = __expf(-__expf(td[h * 64 + lane]));
    u16* Arow = &Ash[lane * LDW];
    float p = 1.f;
#pragma unroll
    for (int i4 = CHL - 4; i4 >= 0; i4 -= 4) {
      float a3 = bf2f(Kp[(size_t)(i4 + 3) * C_]) * p; p *= w;
      float a2 = bf2f(Kp[(size_t)(i4 + 2) * C_]) * p; p *= w;
      float a1 = bf2f(Kp[(size_t)(i4 + 1) * C_]) * p; p *= w;
      float a0 = bf2f(Kp[(size_t)(i4 + 0) * C_]) * p; p *= w;
      ushort4 pk;
      pk.x = f2bf(a0); pk.y = f2bf(a1); pk.z = f2bf(a2); pk.w = f2bf(a3);
      *reinterpret_cast<ushort4*>(&Arow[i4]) = pk;
    }
  }
  {
    u16* Vrow = &Vsh[lane * LDW];
#pragma unroll
    for (int i4 = 0; i4 < CHL; i4 += 4) {
      ushort4 pk;
      pk.x = Vp[(size_t)(i4 + 0) * C_];
      pk.y = Vp[(size_t)(i4 + 1) * C_];
      pk.z = Vp[(size_t)(i4 + 2) * C_];
      pk.w = Vp[(size_t)(i4 + 3) * C_];
      *reinterpret_cast<ushort4*>(&Vrow[i4]) = pk;
    }
  }

  f32x4 acc[4][4];
#pragma unroll
  for (int m = 0; m < 4; m++)
#pragma unroll
    for (int n = 0; n < 4; n++) acc[m][n] = (f32x4){0.f, 0.f, 0.f, 0.f};

#pragma unroll
  for (int kb = 0; kb < CHL / 32; kb++) {
    int ko = kb * 32 + (lane >> 4) * 8;
    bf16x8 Af[4], Bf[4];
#pragma unroll
    for (int m = 0; m < 4; m++) {
      ushort8v t8 = *reinterpret_cast<const ushort8v*>(&Ash[(m * 16 + (lane & 15)) * LDW + ko]);
      Af[m] = __builtin_bit_cast(bf16x8, t8);
    }
#pragma unroll
    for (int n = 0; n < 4; n++) {
      ushort8v t8 = *reinterpret_cast<const ushort8v*>(&Vsh[(n * 16 + (lane & 15)) * LDW + ko]);
      Bf[n] = __builtin_bit_cast(bf16x8, t8);
    }
#pragma unroll
    for (int m = 0; m < 4; m++)
#pragma unroll
      for (int n = 0; n < 4; n++)
        acc[m][n] = __builtin_amdgcn_mfma_f32_16x16x32_bf16(Af[m], Bf[n], acc[m][n], 0, 0, 0);
  }

  float* outp = chunks + (((size_t)c * B_ + b) * H_ + h) * 4096;
  int r0 = (lane >> 4) * 4, c0 = lane & 15;
#pragma unroll
  for (int m = 0; m < 4; m++)
#pragma unroll
    for (int n = 0; n < 4; n++)
#pragma unroll
      for (int q = 0; q < 4; q++)
        outp[(size_t)(m * 16 + r0 + q) * 64 + n * 16 + c0] = acc[m][n][q];
}

// ---------------- scan phase 1 (scalar fallback) ----------------
template <int NCH, int CHL>
__global__ __launch_bounds__(256) void scan_phase1(
    const u16* __restrict__ Kb, const u16* __restrict__ Vb,
    const float* __restrict__ td, float* __restrict__ chunks) {
  int lane = threadIdx.x & 63;
  int gw = (blockIdx.x * 256 + threadIdx.x) >> 6;
  int c = gw & (NCH - 1), bh = gw / NCH;
  int h = bh & 31, b = bh >> 5;
  const float* tdh = td + h * 64;
  float wreg[64];
#pragma unroll
  for (int s = 0; s < 64; s++) wreg[s] = __expf(-__expf(tdh[s]));
  float st[64];
#pragma unroll
  for (int s = 0; s < 64; s++) st[s] = 0.f;
  size_t base = ((size_t)b * T_ + (size_t)c * CHL) * C_ + h * 64 + lane;
  const u16* Kp = Kb + base;
  const u16* Vp = Vb + base;
  for (int t = 0; t < CHL; t++) {
    float kcur = bf2f(Kp[(size_t)t * C_]), vcur = bf2f(Vp[(size_t)t * C_]);
#pragma unroll
    for (int s = 0; s < 64; s++) {
      float ks = __shfl(kcur, s);
      st[s] = fmaf(wreg[s], st[s], ks * vcur);
    }
  }
  float* outp = chunks + (((size_t)c * B_ + b) * H_ + h) * 4096 + lane;
#pragma unroll
  for (int s = 0; s < 64; s++) outp[s * 64] = st[s];
}

// ---------------- scan phase 2 ----------------
template <int NCH, int CHL>
__global__ __launch_bounds__(256) void scan_phase2(
    const float* __restrict__ st0, const float* __restrict__ td,
    float* __restrict__ chunks, float* __restrict__ state_out) {
  int idx = blockIdx.x * 256 + threadIdx.x;
  int h = (idx >> 12) & 31;
  int s = (idx >> 6) & 63;
  float wL = __expf(-(float)CHL * __expf(td[h * 64 + s]));
  float st = st0[idx];
#pragma unroll
  for (int cc = 0; cc < NCH; cc++) {
    size_t off = (size_t)cc * 524288 + idx;
    float sc = chunks[off];
    chunks[off] = st;
    st = fmaf(wL, st, sc);
  }
  state_out[idx] = st;
}

// ---------------- scan phase 3 (MFMA, 4-wave blocks, CHL=64) ----------------
__global__ __launch_bounds__(256) void scan_phase3_mfma(
    const u16* __restrict__ Rb, const u16* __restrict__ Kb,
    const u16* __restrict__ Vb, const float* __restrict__ td,
    const float* __restrict__ tf, const float* __restrict__ chunks,
    const u16* __restrict__ Gb, const float* __restrict__ lnw,
    const float* __restrict__ lnb, u16* __restrict__ Y) {
  __shared__ __align__(16) u16 smem[4][5248];
  int lane = threadIdx.x & 63, wib = threadIdx.x >> 6;
  int gw = blockIdx.x * 4 + wib;
  int c = gw & 31, bh = gw >> 5;
  int h = bh & 31, b = bh >> 5;
  int a = lane & 15, g = lane >> 4;
  int h0 = h * 64;

  u16* Kt = smem[wib];
  u16* Vt = Kt + 1024;
  u16* StT = Vt + 1024;
  u16* AT = StT + 2560;

  f32x8 sA[2], sB[2], sC[2], uA[2];
#pragma unroll
  for (int kk = 0; kk < 2; kk++) {
#pragma unroll
    for (int e = 0; e < 8; e++) {
      int s = kk * 32 + g * 8 + e;
      float ew = __expf(td[h0 + s]);
      sA[kk][e] = __expf(-(float)a * ew);
      sB[kk][e] = __expf(-((float)a - 8.f) * ew);
      sC[kk][e] = __expf(-(7.f - (float)a) * ew);
      uA[kk][e] = tf[h0 + s];
    }
  }
  f32x4 sE[4];
  f32x4 ewD;
#pragma unroll
  for (int ms = 0; ms < 4; ms++) {
    ewD[ms] = __expf(td[h0 + ms * 16 + a]);
#pragma unroll
    for (int q = 0; q < 4; q++)
      sE[ms][q] = __expf(-16.f * __expf(td[h0 + ms * 16 + g * 4 + q]));
  }
  float lwv[4], lbv[4];
#pragma unroll
  for (int nd = 0; nd < 4; nd++) {
    lwv[nd] = lnw[h0 + nd * 16 + a];
    lbv[nd] = lnb[h0 + nd * 16 + a];
  }

  f32x4 St[4][4];
  const float* cpc = chunks + (((size_t)c * B_ + b) * H_ + h) * 4096;
#pragma unroll
  for (int ms = 0; ms < 4; ms++)
#pragma unroll
    for (int nd = 0; nd < 4; nd++)
#pragma unroll
      for (int q = 0; q < 4; q++)
        St[ms][nd][q] = cpc[(size_t)(ms * 16 + g * 4 + q) * 64 + nd * 16 + a];

#pragma unroll
  for (int z = 0; z < 6; z++) {
    int idx = z * 64 + lane;
    int row = idx / 24, col = 16 + idx % 24;
    AT[row * 40 + col] = 0;
  }

  size_t tbase = ((size_t)b * T_ + (size_t)c * 64) * C_ + h0;

  for (int sb = 0; sb < 4; sb++) {
    size_t rb0 = tbase + (size_t)(sb * 16) * C_;

    ushort8v r8[2], k8[2];
#pragma unroll
    for (int kk = 0; kk < 2; kk++) {
      r8[kk] = *reinterpret_cast<const ushort8v*>(Rb + rb0 + (size_t)a * C_ + kk * 32 + g * 8);
      k8[kk] = *reinterpret_cast<const ushort8v*>(Kb + rb0 + (size_t)a * C_ + kk * 32 + g * 8);
    }
    {
      int srow = lane >> 3;
      int scol = (lane & 7) * 8;
      *reinterpret_cast<ushort8v*>(&Kt[srow * 64 + scol]) =
          *reinterpret_cast<const ushort8v*>(Kb + rb0 + (size_t)srow * C_ + scol);
      *reinterpret_cast<ushort8v*>(&Kt[(srow + 8) * 64 + scol]) =
          *reinterpret_cast<const ushort8v*>(Kb + rb0 + (size_t)(srow + 8) * C_ + scol);
      *reinterpret_cast<ushort8v*>(&Vt[srow * 64 + scol]) =
          *reinterpret_cast<const ushort8v*>(Vb + rb0 + (size_t)srow * C_ + scol);
      *reinterpret_cast<ushort8v*>(&Vt[(srow + 8) * 64 + scol]) =
          *reinterpret_cast<const ushort8v*>(Vb + rb0 + (size_t)(srow + 8) * C_ + scol);
    }

    f32x4 O[4];
#pragma unroll
    for (int nd = 0; nd < 4; nd++) O[nd] = (f32x4){0.f, 0.f, 0.f, 0.f};

#pragma unroll
    for (int kk = 0; kk < 2; kk++) {
#pragma unroll
      for (int msl = 0; msl < 2; msl++) {
        int ms = kk * 2 + msl;
#pragma unroll
        for (int nd = 0; nd < 4; nd++) {
          ushort4 pk;
          pk.x = f2bf(St[ms][nd][0]); pk.y = f2bf(St[ms][nd][1]);
          pk.z = f2bf(St[ms][nd][2]); pk.w = f2bf(St[ms][nd][3]);
          *reinterpret_cast<ushort4*>(&StT[(a + nd * 16) * 40 + msl * 16 + g * 4]) = pk;
        }
      }
      ushort8v rt;
#pragma unroll
      for (int e = 0; e < 8; e++) rt[e] = f2bf(bf2f(r8[kk][e]) * sA[kk][e]);
      bf16x8 rtf = __builtin_bit_cast(bf16x8, rt);
#pragma unroll
      for (int nd = 0; nd < 4; nd++) {
        ushort8v sfr = *reinterpret_cast<const ushort8v*>(&StT[(a + nd * 16) * 40 + g * 8]);
        O[nd] = __builtin_amdgcn_mfma_f32_16x16x32_bf16(
            rtf, __builtin_bit_cast(bf16x8, sfr), O[nd], 0, 0, 0);
      }
    }

    float p = 0.f;
#pragma unroll
    for (int kk = 0; kk < 2; kk++)
#pragma unroll
      for (int e = 0; e < 8; e++)
        p = fmaf(bf2f(r8[kk][e]) * uA[kk][e], bf2f(k8[kk][e]), p);
    p += __shfl_xor(p, 16);
    p += __shfl_xor(p, 32);

    f32x4 Am = (f32x4){0.f, 0.f, 0.f, 0.f};
#pragma unroll
    for (int kk = 0; kk < 2; kk++) {
      ushort8v kh, rh;
#pragma unroll
      for (int e = 0; e < 8; e++) {
        kh[e] = f2bf(bf2f(k8[kk][e]) * sC[kk][e]);
        rh[e] = f2bf(bf2f(r8[kk][e]) * sB[kk][e]);
      }
      Am = __builtin_amdgcn_mfma_f32_16x16x32_bf16(
          __builtin_bit_cast(bf16x8, kh), __builtin_bit_cast(bf16x8, rh), Am, 0, 0, 0);
    }
    {
      ushort4 aw;
#pragma unroll
      for (int q = 0; q < 4; q++) {
        int jr = g * 4 + q;
        float v = (jr < a) ? Am[q] : ((jr == a) ? p : 0.f);
        ((u16*)&aw)[q] = f2bf(v);
      }
      *reinterpret_cast<ushort4*>(&AT[a * 40 + g * 4]) = aw;
    }
    bf16x8 afrag;
    {
      ushort8v t8 = *reinterpret_cast<const ushort8v*>(&AT[a * 40 + g * 8]);
      afrag = __builtin_bit_cast(bf16x8, t8);
    }

    bf16x8 vfrag[4];
#pragma unroll
    for (int nd = 0; nd < 4; nd++) {
      ushort8v t8;
      if (g < 2) {
#pragma unroll
        for (int e = 0; e < 8; e++) t8[e] = Vt[(g * 8 + e) * 64 + a + nd * 16];
      } else {
#pragma unroll
        for (int e = 0; e < 8; e++) t8[e] = 0;
      }
      vfrag[nd] = __builtin_bit_cast(bf16x8, t8);
    }

#pragma unroll
    for (int nd = 0; nd < 4; nd++)
      O[nd] = __builtin_amdgcn_mfma_f32_16x16x32_bf16(afrag, vfrag[nd], O[nd], 0, 0, 0);

#pragma unroll
    for (int ms = 0; ms < 4; ms++)
#pragma unroll
      for (int nd = 0; nd < 4; nd++)
#pragma unroll
        for (int q = 0; q < 4; q++) St[ms][nd][q] *= sE[ms][q];

#pragma unroll
    for (int ms = 0; ms < 4; ms++) {
      ushort8v kt8;
      if (g < 2) {
#pragma unroll
        for (int e = 0; e < 8; e++) {
          int j = g * 8 + e;
          float f = bf2f(Kt[j * 64 + ms * 16 + a]) * __expf(-(15.f - (float)j) * ewD[ms]);
          kt8[e] = f2bf(f);
        }
      } else {
#pragma unroll
        for (int e = 0; e < 8; e++) kt8[e] = 0;
      }
      bf16x8 kf = __builtin_bit_cast(bf16x8, kt8);
#pragma unroll
      for (int nd = 0; nd < 4; nd++)
        St[ms][nd] = __builtin_amdgcn_mfma_f32_16x16x32_bf16(kf, vfrag[nd], St[ms][nd], 0, 0, 0);
    }

#pragma unroll
    for (int nd = 0; nd < 4; nd++)
#pragma unroll
      for (int q = 0; q < 4; q++) O[nd][q] *= 0.125f;
#pragma unroll
    for (int q = 0; q < 4; q++) {
      float ssum = O[0][q] + O[1][q] + O[2][q] + O[3][q];
      ssum += __shfl_xor(ssum, 1); ssum += __shfl_xor(ssum, 2);
      ssum += __shfl_xor(ssum, 4); ssum += __shfl_xor(ssum, 8);
      float mean = ssum * (1.f / 64.f);
      float vv = 0.f;
#pragma unroll
      for (int nd = 0; nd < 4; nd++) {
        float d = O[nd][q] - mean;
        vv = fmaf(d, d, vv);
      }
      vv += __shfl_xor(vv, 1); vv += __shfl_xor(vv, 2);
      vv += __shfl_xor(vv, 4); vv += __shfl_xor(vv, 8);
      float rs = rsqrtf(vv * (1.f / 64.f) + 1e-5f);
      size_t rowoff = rb0 + (size_t)(g * 4 + q) * C_;
#pragma unroll
      for (int nd = 0; nd < 4; nd++) {
        float xn = (O[nd][q] - mean) * rs;
        float gv = bf2f(Gb[rowoff + nd * 16 + a]);
        float sg = gv / (1.f + __expf(-gv));
        Y[rowoff + nd * 16 + a] = f2bf((xn * lwv[nd] + lbv[nd]) * sg);
      }
    }
  }
}

// ---------------- scan phase 3 (scalar fallback, NCH16) ----------------
template <int NCH, int CHL>
__global__ __launch_bounds__(256) void scan_phase3(
    const u16* __restrict__ Rb, const u16* __restrict__ Kb,
    const u16* __restrict__ Vb, const float* __restrict__ td,
    const float* __restrict__ tf, const float* __restrict__ chunks,
    const u16* __restrict__ Gb, const float* __restrict__ lnw,
    const float* __restrict__ lnb, u16* __restrict__ Y) {
  int lane = threadIdx.x & 63;
  int gw = (blockIdx.x * 256 + threadIdx.x) >> 6;
  int c = gw & (NCH - 1), bh = gw / NCH;
  int h = bh & 31, b = bh >> 5;
  const float* tdh = td + h * 64;
  float wreg[64];
#pragma unroll
  for (int s = 0; s < 64; s++) wreg[s] = __expf(-__expf(tdh[s]));
  float u_own = tf[h * 64 + lane];
  float lw = lnw[h * 64 + lane];
  float lb = lnb[h * 64 + lane];
  float st[64];
  const float* cp = chunks + (((size_t)c * B_ + b) * H_ + h) * 4096 + lane;
#pragma unroll
  for (int s = 0; s < 64; s++) st[s] = cp[s * 64];
  size_t base = ((size_t)b * T_ + (size_t)c * CHL) * C_ + h * 64 + lane;
  const u16* Rp = Rb + base;
  const u16* Kp = Kb + base;
  const u16* Vp = Vb + base;
  const u16* Gp = Gb + base;
  u16* Yp = Y + base;
  for (int t = 0; t < CHL; t++) {
    float rcur = bf2f(Rp[(size_t)t * C_]);
    float kcur = bf2f(Kp[(size_t)t * C_]);
    float vcur = bf2f(Vp[(size_t)t * C_]);
    float p = rcur * u_own * kcur;
#pragma unroll
    for (int off = 32; off >= 1; off >>= 1) p += __shfl_xor(p, off);
    float acc = 0.f;
#pragma unroll
    for (int s = 0; s < 64; s++) {
      float rs = __shfl(rcur, s);
      float ks = __shfl(kcur, s);
      acc = fmaf(rs, st[s], acc);
      st[s] = fmaf(wreg[s], st[s], ks * vcur);
    }
    float o = fmaf(p, vcur, acc);
    float x = o * 0.125f;
    float sum = x;
#pragma unroll
    for (int off = 32; off >= 1; off >>= 1) sum += __shfl_xor(sum, off);
    float mean = sum * (1.f / 64.f);
    float d = x - mean;
    float v2 = d * d;
#pragma unroll
    for (int off = 32; off >= 1; off >>= 1) v2 += __shfl_xor(v2, off);
    float var = v2 * (1.f / 64.f);
    float xn = d * rsqrtf(var + 1e-5f);
    float gg = bf2f(Gp[(size_t)t * C_]);
    float sg = gg / (1.f + __expf(-gg));
    Yp[(size_t)t * C_] = f2bf((xn * lw + lb) * sg);
  }
}

extern "C" void kernel_launch(void* const* d_in, const int* in_sizes, int n_in,
                              void* d_out, int out_size, void* d_ws, size_t ws_size,
                              hipStream_t stream) {
  const float* hidden = (const float*)d_in[0];
  const float* state0 = (const float*)d_in[1];
  const float* td = (const float*)d_in[2];
  const float* tf = (const float*)d_in[3];
  const float* mk = (const float*)d_in[4];
  const float* mv = (const float*)d_in[5];
  const float* mr = (const float*)d_in[6];
  const float* mg = (const float*)d_in[7];
  const float* kw = (const float*)d_in[8];
  const float* vw = (const float*)d_in[9];
  const float* rw = (const float*)d_in[10];
  const float* gw = (const float*)d_in[11];
  const float* ow = (const float*)d_in[12];
  const float* lnw = (const float*)d_in[13];
  const float* lnb = (const float*)d_in[14];

  float* out = (float*)d_out;
  float* state_f = out + (size_t)B_ * T_ * C_;

  const size_t BUF = (size_t)B_ * T_ * C_ * 2;       // 33,554,432 B
  const size_t WBUF = (size_t)C_ * C_ * 2;           // 8,388,608 B
  const size_t needOpt = 7 * BUF + WBUF;             // 243,269,632 B

  dim3 blk(256);
  int mixGrid = (B_ * T_ * C_ / 4) / 256;
  int convN4 = C_ * C_ / 4;
  int convGrid = convN4 / 256;
  int gemmGrid = (B_ * T_ / 256) * (C_ / 256);
  dim3 gblk(512);

  if (ws_size >= needOpt) {
    char* base = (char*)d_ws;
    u16* mixG = (u16*)(base + 0 * BUF);          // A
    u16* mixR = (u16*)(base + 1 * BUF);          // B
    u16* mixK = (u16*)(base + 2 * BUF);          // C
    u16* mixV = (u16*)(base + 3 * BUF);          // D
    u16* wb   = (u16*)(base + 4 * BUF);
    u16* gb   = (u16*)(base + 4 * BUF + WBUF);
    u16* kb   = (u16*)(base + 5 * BUF + WBUF);
    u16* vb   = (u16*)(base + 6 * BUF + WBUF);
    u16* rb   = mixG;                            // alias A (dead after G-gemm)
    u16* Y    = mixR;                            // alias B (dead after R-gemm)
    float* chunks = (float*)(base + 2 * BUF);    // alias C+D (dead after K,V-gemms)

    mix4p_cast_kernel<<<B_ * T_, blk, 0, stream>>>(hidden, mk, mv, mr, mg,
                                                   mixK, mixV, mixR, mixG);
    conv_bf16_kernel<<<convGrid, blk, 0, stream>>>(gw, wb, convN4);
    gemm_bt256<u16><<<gemmGrid, gblk, 0, stream>>>(mixG, wb, gb, B_ * T_, C_, C_);
    conv_bf16_kernel<<<convGrid, blk, 0, stream>>>(rw, wb, convN4);
    gemm_bt256<u16><<<gemmGrid, gblk, 0, stream>>>(mixR, wb, rb, B_ * T_, C_, C_);
    conv_bf16_kernel<<<convGrid, blk, 0, stream>>>(kw, wb, convN4);
    gemm_bt256<u16><<<gemmGrid, gblk, 0, stream>>>(mixK, wb, kb, B_ * T_, C_, C_);
    conv_bf16_kernel<<<convGrid, blk, 0, stream>>>(vw, wb, convN4);
    gemm_bt256<u16><<<gemmGrid, gblk, 0, stream>>>(mixV, wb, vb, B_ * T_, C_, C_);

    scan_phase1_mfma<64><<<B_ * H_ * 32, dim3(64), 0, stream>>>(kb, vb, td, chunks);
    scan_phase2<32, 64><<<2048, blk, 0, stream>>>(state0, td, chunks, state_f);
    scan_phase3_mfma<<<(B_ * H_ * 32) / 4, blk, 0, stream>>>(rb, kb, vb, td, tf, chunks, gb, lnw, lnb, Y);

    conv_bf16_kernel<<<convGrid, blk, 0, stream>>>(ow, wb, convN4);
    gemm_bt256<float><<<gemmGrid, gblk, 0, stream>>>(Y, wb, out, B_ * T_, C_, C_);
    return;
  }

  // minimal fallback (~209.7 MB): NCH16 scalar scans, serialized mixes
  char* ws = (char*)d_ws;
  u16* mixA = (u16*)ws;    ws += BUF;
  u16* wb = (u16*)ws;      ws += WBUF;
  u16* rb = (u16*)ws;      ws += BUF;
  u16* kb = (u16*)ws;      ws += BUF;
  u16* vb = (u16*)ws;      ws += BUF;
  u16* gb = (u16*)ws;      ws += BUF;
  float* chunks = (float*)ws;

  mix_cast_kernel<<<mixGrid, blk, 0, stream>>>(hidden, mr, mixA);
  conv_bf16_kernel<<<convGrid, blk, 0, stream>>>(rw, wb, convN4);
  gemm_bt256<u16><<<gemmGrid, gblk, 0, stream>>>(mixA, wb, rb, B_ * T_, C_, C_);
  mix_cast_kernel<<<mixGrid, blk, 0, stream>>>(hidden, mk, mixA);
  conv_bf16_kernel<<<convGrid, blk, 0, stream>>>(kw, wb, convN4);
  gemm_bt256<u16><<<gemmGrid, gblk, 0, stream>>>(mixA, wb, kb, B_ * T_, C_, C_);
  mix_cast_kernel<<<mixGrid, blk, 0, stream>>>(hidden, mv, mixA);
  conv_bf16_kernel<<<convGrid, blk, 0, stream>>>(vw, wb, convN4);
  gemm_bt256<u16><<<gemmGrid, gblk, 0, stream>>>(mixA, wb, vb, B_ * T_, C_, C_);
  mix_cast_kernel<<<mixGrid, blk, 0, stream>>>(hidden, mg, mixA);
  conv_bf16_kernel<<<convGrid, blk, 0, stream>>>(gw, wb, convN4);
  gemm_bt256<u16><<<gemmGrid, gblk, 0, stream>>>(mixA, wb, gb, B_ * T_, C_, C_);

  scan_phase1<16, 128><<<(B_ * H_ * 16) / 4, blk, 0, stream>>>(kb, vb, td, chunks);
  scan_phase2<16, 128><<<2048, blk, 0, stream>>>(state0, td, chunks, state_f);
  scan_phase3<16, 128><<<(B_ * H_ * 16) / 4, blk, 0, stream>>>(rb, kb, vb, td, tf, chunks, gb, lnw, lnb, mixA);

  conv_bf16_kernel<<<convGrid, blk, 0, stream>>>(ow, wb, convN4);
  gemm_bt256<float><<<gemmGrid, gblk, 0, stream>>>(mixA, wb, out, B_ * T_, C_, C_);
}

// Round 24
// 594.330 us; speedup vs baseline: 8.2776x; 1.0278x over previous
//
#include <hip/hip_runtime.h>
#include <hip/hip_bf16.h>

typedef unsigned short u16;
typedef __bf16 bf16x8 __attribute__((ext_vector_type(8)));
typedef unsigned short ushort8v __attribute__((ext_vector_type(8)));
typedef float f32x4 __attribute__((ext_vector_type(4)));
typedef float f32x8 __attribute__((ext_vector_type(8)));

#define B_ 4
#define T_ 2048
#define C_ 2048
#define H_ 32
#define S_ 64

__device__ __forceinline__ u16 f2bf(float x) {
  __bf16 b = (__bf16)x;  // native RNE conversion
  return __builtin_bit_cast(u16, b);
}
__device__ __forceinline__ float bf2f(u16 x) {
  return __uint_as_float(((unsigned int)x) << 16);
}
__device__ __forceinline__ void gload_lds16(const void* g, void* l) {
  __builtin_amdgcn_global_load_lds(
      (const __attribute__((address_space(1))) void*)g,
      (__attribute__((address_space(3))) void*)l, 16, 0, 0);
}

#define VM10 asm volatile("s_waitcnt vmcnt(10)" ::: "memory")
#define VM8 asm volatile("s_waitcnt vmcnt(8)" ::: "memory")
#define VM0 asm volatile("s_waitcnt vmcnt(0)" ::: "memory")
#define LGKM0 asm volatile("s_waitcnt lgkmcnt(0)" ::: "memory")
#define BARR __builtin_amdgcn_s_barrier()
#define SCB __builtin_amdgcn_sched_barrier(0)

// ---------------- single mix + cast to bf16 (fallback path) ----------------
__global__ __launch_bounds__(256) void mix_cast_kernel(
    const float* __restrict__ hidden, const float* __restrict__ mixp,
    u16* __restrict__ out) {
  int idx = blockIdx.x * 256 + threadIdx.x;
  int c4 = idx & 511;
  int bt = idx >> 9;
  int t = bt & (T_ - 1);
  float4 h = reinterpret_cast<const float4*>(hidden)[idx];
  float4 m = reinterpret_cast<const float4*>(mixp)[c4];
  float4 sh = make_float4(0.f, 0.f, 0.f, 0.f);
  if (t != 0) sh = reinterpret_cast<const float4*>(hidden)[idx - 512];
  ushort4 o;
  o.x = f2bf(h.x * m.x + sh.x * (1.f - m.x));
  o.y = f2bf(h.y * m.y + sh.y * (1.f - m.y));
  o.z = f2bf(h.z * m.z + sh.z * (1.f - m.z));
  o.w = f2bf(h.w * m.w + sh.w * (1.f - m.w));
  reinterpret_cast<ushort4*>(out)[idx] = o;
}

// ---------------- fused 4-way mix + cast, row-paired (1.5 reads/row) ----------------
__global__ __launch_bounds__(256) void mix4p_cast_kernel(
    const float* __restrict__ hidden,
    const float* __restrict__ mK, const float* __restrict__ mV,
    const float* __restrict__ mR, const float* __restrict__ mG,
    u16* __restrict__ oK, u16* __restrict__ oV,
    u16* __restrict__ oR, u16* __restrict__ oG) {
  int bid = blockIdx.x;            // 8192 = (B*T/2) * 2 col-halves
  int colh = bid & 1;
  int rp = bid >> 1;               // row pair index
  int c4 = colh * 256 + threadIdx.x;   // 0..511
  int bt0 = rp * 2;
  int t0 = bt0 & (T_ - 1);
  size_t i0 = (size_t)bt0 * 512 + c4;
  float4 h0 = reinterpret_cast<const float4*>(hidden)[i0];
  float4 h1 = reinterpret_cast<const float4*>(hidden)[i0 + 512];
  float4 hp = make_float4(0.f, 0.f, 0.f, 0.f);
  if (t0 != 0) hp = reinterpret_cast<const float4*>(hidden)[i0 - 512];
  float4 m;
  ushort4 o0, o1;
#define DOMIX2(MP, OP)                                           \
  m = reinterpret_cast<const float4*>(MP)[c4];                   \
  o0.x = f2bf(h0.x * m.x + hp.x * (1.f - m.x));                  \
  o0.y = f2bf(h0.y * m.y + hp.y * (1.f - m.y));                  \
  o0.z = f2bf(h0.z * m.z + hp.z * (1.f - m.z));                  \
  o0.w = f2bf(h0.w * m.w + hp.w * (1.f - m.w));                  \
  o1.x = f2bf(h1.x * m.x + h0.x * (1.f - m.x));                  \
  o1.y = f2bf(h1.y * m.y + h0.y * (1.f - m.y));                  \
  o1.z = f2bf(h1.z * m.z + h0.z * (1.f - m.z));                  \
  o1.w = f2bf(h1.w * m.w + h0.w * (1.f - m.w));                  \
  reinterpret_cast<ushort4*>(OP)[i0] = o0;                       \
  reinterpret_cast<ushort4*>(OP)[i0 + 512] = o1;
  DOMIX2(mK, oK)
  DOMIX2(mV, oV)
  DOMIX2(mR, oR)
  DOMIX2(mG, oG)
#undef DOMIX2
}

// ---------------- fp32 -> bf16 weight cast (single) ----------------
__global__ __launch_bounds__(256) void conv_bf16_kernel(
    const float* __restrict__ in, u16* __restrict__ out, int n4) {
  int i = blockIdx.x * 256 + threadIdx.x;
  if (i >= n4) return;
  float4 v = reinterpret_cast<const float4*>(in)[i];
  ushort4 o;
  o.x = f2bf(v.x); o.y = f2bf(v.y); o.z = f2bf(v.z); o.w = f2bf(v.w);
  reinterpret_cast<ushort4*>(out)[i] = o;
}

// ---------------- fused 3-weight fp32 -> bf16 cast ----------------
__global__ __launch_bounds__(256) void conv3_bf16_kernel(
    const float* __restrict__ w0, const float* __restrict__ w1,
    const float* __restrict__ w2,
    u16* __restrict__ o0, u16* __restrict__ o1, u16* __restrict__ o2) {
  int wsel = blockIdx.x >> 12;             // 4096 blocks per weight
  int i = (blockIdx.x & 4095) * 256 + threadIdx.x;
  const float* in = (wsel == 0) ? w0 : (wsel == 1) ? w1 : w2;
  u16* out = (wsel == 0) ? o0 : (wsel == 1) ? o1 : o2;
  float4 v = reinterpret_cast<const float4*>(in)[i];
  ushort4 o;
  o.x = f2bf(v.x); o.y = f2bf(v.y); o.z = f2bf(v.z); o.w = f2bf(v.w);
  reinterpret_cast<ushort4*>(out)[i] = o;
}

// ---------------- 256x256 bf16 GEMM (r15 schedule + fragment prefetch;
// LDS epilogues for both output types, XOR-swizzled) ----------
template <typename OT>
__global__ __launch_bounds__(512, 2) void gemm_bt256(
    const u16* __restrict__ A, const u16* __restrict__ Bm,
    OT* __restrict__ C, int M, int N, int K) {
  __shared__ u16 Asl[4][8192];
  __shared__ u16 Bsl[4][8192];
  const int tid = threadIdx.x, lane = tid & 63, w = tid >> 6;
  const int wr = w >> 2, wc = w & 3;
  const int a15 = lane & 15, g4 = lane >> 4;
  const int nbn = N >> 8;
  const int nwg = gridDim.x, bid = blockIdx.x, cpx = nwg >> 3;
  const int swz = (bid & 7) * cpx + (bid >> 3);
  const int bm = swz / nbn, bn = swz % nbn;
  const int Ar0 = bm * 256, Br0 = bn * 256;

  const int rowoff = w * 32 + (lane >> 2);
  const int colswz = ((lane & 3) ^ ((lane >> 3) & 3)) * 8;
  const u16* Agl = A + (size_t)(Ar0 + rowoff) * K + colswz;
  const u16* Bgl = Bm + (size_t)(Br0 + rowoff) * K + colswz;
  const int lb = w * 1024;

  const int rdc = (((lane >> 4) ^ ((lane >> 1) & 3))) * 8;
  const int arow = wr * 128 + a15;
  const int brow = wc * 64 + a15;

  f32x4 acc[8][4];
#pragma unroll
  for (int m = 0; m < 8; m++)
#pragma unroll
    for (int n = 0; n < 4; n++) acc[m][n] = (f32x4){0.f, 0.f, 0.f, 0.f};

  auto STA = [&](int ktile, int kk, int slot) {
    const u16* g = Agl + ktile * 64 + kk * 32;
    gload_lds16(g, &Asl[slot][lb]);
    gload_lds16(g + (size_t)16 * K, &Asl[slot][lb + 512]);
  };
  auto STB = [&](int ktile, int kk, int slot) {
    const u16* g = Bgl + ktile * 64 + kk * 32;
    gload_lds16(g, &Bsl[slot][lb]);
    gload_lds16(g + (size_t)16 * K, &Bsl[slot][lb + 512]);
  };
  auto LOADF = [&](int P, int kk, bf16x8 (&af)[8], bf16x8 (&bv)[4]) {
    const u16* As_ = Asl[P * 2 + kk];
    const u16* Bs_ = Bsl[P * 2 + kk];
#pragma unroll
    for (int mf = 0; mf < 8; mf++)
      af[mf] = __builtin_bit_cast(
          bf16x8, *reinterpret_cast<const ushort8v*>(&As_[(arow + mf * 16) * 32 + rdc]));
#pragma unroll
    for (int nf = 0; nf < 4; nf++)
      bv[nf] = __builtin_bit_cast(
          bf16x8, *reinterpret_cast<const ushort8v*>(&Bs_[(brow + nf * 16) * 32 + rdc]));
  };
  auto MM = [&](bf16x8 (&af)[8], bf16x8 (&bv)[4]) {
    __builtin_amdgcn_s_setprio(1);
#pragma unroll
    for (int mf = 0; mf < 8; mf++)
#pragma unroll
      for (int nf = 0; nf < 4; nf++)
        acc[mf][nf] =
            __builtin_amdgcn_mfma_f32_16x16x32_bf16(af[mf], bv[nf], acc[mf][nf], 0, 0, 0);
    __builtin_amdgcn_s_setprio(0);
  };

  bf16x8 f0A[8], f1A[8];
  bf16x8 f0B[4], f1B[4];

  const int NT = K >> 6;
  STA(0, 0, 0); STB(0, 0, 0);
  STA(0, 1, 1); STB(0, 1, 1);
  STA(1, 0, 2); STB(1, 0, 2);
  VM8;
  BARR;
  LOADF(0, 0, f0A, f0B);

  for (int T = 0; T + 2 < NT; ++T) {
    int P = T & 1, Q = P ^ 1;
    STA(T + 1, 1, Q * 2 + 1); STB(T + 1, 1, Q * 2 + 1);
    VM10; BARR; SCB;
    LOADF(P, 1, f1A, f1B);
    MM(f0A, f0B);
    BARR;
    STA(T + 2, 0, P * 2 + 0); STB(T + 2, 0, P * 2 + 0);
    VM10; BARR; SCB;
    LOADF(Q, 0, f0A, f0B);
    MM(f1A, f1B);
    BARR;
  }
  {
    int T = NT - 2, P = T & 1, Q = P ^ 1;
    STA(T + 1, 1, Q * 2 + 1); STB(T + 1, 1, Q * 2 + 1);
    VM10; BARR; SCB;
    LOADF(P, 1, f1A, f1B);
    MM(f0A, f0B);
    BARR;
    VM8; BARR; SCB;
    LOADF(Q, 0, f0A, f0B);
    MM(f1A, f1B);
    BARR;
  }
  {
    int P = (NT - 1) & 1;
    VM0; BARR; SCB;
    LOADF(P, 1, f1A, f1B);
    MM(f0A, f0B);
    LGKM0;
    BARR;
    MM(f1A, f1B);
  }

  if constexpr (sizeof(OT) == 2) {
    // wave-private 16KB region; col XOR (g4<<4) -> 2-way banks (free)
    u16* ep = (w < 4) ? Asl[w] : Bsl[w - 4];
#pragma unroll
    for (int mfg = 0; mfg < 8; mfg++)
#pragma unroll
      for (int q = 0; q < 4; q++)
#pragma unroll
        for (int nf = 0; nf < 4; nf++)
          ep[(mfg * 16 + g4 * 4 + q) * 64 + ((nf * 16 + a15) ^ (g4 << 4))] =
              f2bf(acc[mfg][nf][q]);
    OT* cbase = C + (size_t)(Ar0 + wr * 128) * N + Br0 + wc * 64;
#pragma unroll
    for (int i = 0; i < 16; i++) {
      int id = lane + 64 * i;
      int row = id >> 3, k16 = id & 7;
      int pc = (k16 * 8) ^ (((row >> 2) & 3) << 4);
      ushort8v v8 = *reinterpret_cast<const ushort8v*>(&ep[row * 64 + pc]);
      *reinterpret_cast<ushort8v*>(cbase + (size_t)row * N + k16 * 8) = v8;
    }
  } else {
    // fp32: two 16KB halves (64x64 f32), same XOR swizzle, coalesced dwordx4
    float* epf = reinterpret_cast<float*>((w < 4) ? Asl[w] : Bsl[w - 4]);
#pragma unroll
    for (int half = 0; half < 2; half++) {
#pragma unroll
      for (int mm = 0; mm < 4; mm++) {
        int mfg = half * 4 + mm;
#pragma unroll
        for (int q = 0; q < 4; q++)
#pragma unroll
          for (int nf = 0; nf < 4; nf++)
            epf[(mm * 16 + g4 * 4 + q) * 64 + ((nf * 16 + a15) ^ (g4 << 4))] =
                acc[mfg][nf][q];
      }
      OT* cbase = C + (size_t)(Ar0 + wr * 128 + half * 64) * N + Br0 + wc * 64;
#pragma unroll
      for (int i = 0; i < 16; i++) {
        int id = lane + 64 * i;
        int row = id >> 4, c4 = id & 15;
        int pc = (c4 * 4) ^ (((row >> 2) & 3) << 4);
        float4 v = *reinterpret_cast<const float4*>(&epf[row * 64 + pc]);
        *reinterpret_cast<float4*>(cbase + (size_t)row * N + c4 * 4) = v;
      }
      if (half == 0) { LGKM0; }
    }
  }
}

// ---------------- scan phase 1 (MFMA, 1-wave blocks) ----------------
template <int CHL>
__global__ __launch_bounds__(64) void scan_phase1_mfma(
    const u16* __restrict__ Kb, const u16* __restrict__ Vb,
    const float* __restrict__ td, float* __restrict__ chunks) {
  constexpr int NCH = T_ / CHL;
  constexpr int LDW = CHL + 8;
  __shared__ u16 Ash[64 * LDW];
  __shared__ u16 Vsh[64 * LDW];
  int lane = threadIdx.x & 63;
  int gw = blockIdx.x;
  int c = gw & (NCH - 1), bh = gw / NCH;
  int h = bh & 31, b = bh >> 5;

  size_t base = ((size_t)b * T_ + (size_t)c * CHL) * C_ + h * 64 + lane;
  const u16* Kp = Kb + base;
  const u16* Vp = Vb + base;

  {
    float w = __expf(-__expf(td[h * 64 + lane]));
    u16* Arow = &Ash[lane * LDW];
    float p = 1.f;
#pragma unroll
    for (int i4 = CHL - 4; i4 >= 0; i4 -= 4) {
      float a3 = bf2f(Kp[(size_t)(i4 + 3) * C_]) * p; p *= w;
      float a2 = bf2f(Kp[(size_t)(i4 + 2) * C_]) * p; p *= w;
      float a1 = bf2f(Kp[(size_t)(i4 + 1) * C_]) * p; p *= w;
      float a0 = bf2f(Kp[(size_t)(i4 + 0) * C_]) * p; p *= w;
      ushort4 pk;
      pk.x = f2bf(a0); pk.y = f2bf(a1); pk.z = f2bf(a2); pk.w = f2bf(a3);
      *reinterpret_cast<ushort4*>(&Arow[i4]) = pk;
    }
  }
  {
    u16* Vrow = &Vsh[lane * LDW];
#pragma unroll
    for (int i4 = 0; i4 < CHL; i4 += 4) {
      ushort4 pk;
      pk.x = Vp[(size_t)(i4 + 0) * C_];
      pk.y = Vp[(size_t)(i4 + 1) * C_];
      pk.z = Vp[(size_t)(i4 + 2) * C_];
      pk.w = Vp[(size_t)(i4 + 3) * C_];
      *reinterpret_cast<ushort4*>(&Vrow[i4]) = pk;
    }
  }

  f32x4 acc[4][4];
#pragma unroll
  for (int m = 0; m < 4; m++)
#pragma unroll
    for (int n = 0; n < 4; n++) acc[m][n] = (f32x4){0.f, 0.f, 0.f, 0.f};

#pragma unroll
  for (int kb = 0; kb < CHL / 32; kb++) {
    int ko = kb * 32 + (lane >> 4) * 8;
    bf16x8 Af[4], Bf[4];
#pragma unroll
    for (int m = 0; m < 4; m++) {
      ushort8v t8 = *reinterpret_cast<const ushort8v*>(&Ash[(m * 16 + (lane & 15)) * LDW + ko]);
      Af[m] = __builtin_bit_cast(bf16x8, t8);
    }
#pragma unroll
    for (int n = 0; n < 4; n++) {
      ushort8v t8 = *reinterpret_cast<const ushort8v*>(&Vsh[(n * 16 + (lane & 15)) * LDW + ko]);
      Bf[n] = __builtin_bit_cast(bf16x8, t8);
    }
#pragma unroll
    for (int m = 0; m < 4; m++)
#pragma unroll
      for (int n = 0; n < 4; n++)
        acc[m][n] = __builtin_amdgcn_mfma_f32_16x16x32_bf16(Af[m], Bf[n], acc[m][n], 0, 0, 0);
  }

  float* outp = chunks + (((size_t)c * B_ + b) * H_ + h) * 4096;
  int r0 = (lane >> 4) * 4, c0 = lane & 15;
#pragma unroll
  for (int m = 0; m < 4; m++)
#pragma unroll
    for (int n = 0; n < 4; n++)
#pragma unroll
      for (int q = 0; q < 4; q++)
        outp[(size_t)(m * 16 + r0 + q) * 64 + n * 16 + c0] = acc[m][n][q];
}

// ---------------- scan phase 1 (scalar fallback) ----------------
template <int NCH, int CHL>
__global__ __launch_bounds__(256) void scan_phase1(
    const u16* __restrict__ Kb, const u16* __restrict__ Vb,
    const float* __restrict__ td, float* __restrict__ chunks) {
  int lane = threadIdx.x & 63;
  int gw = (blockIdx.x * 256 + threadIdx.x) >> 6;
  int c = gw & (NCH - 1), bh = gw / NCH;
  int h = bh & 31, b = bh >> 5;
  const float* tdh = td + h * 64;
  float wreg[64];
#pragma unroll
  for (int s = 0; s < 64; s++) wreg[s] = __expf(-__expf(tdh[s]));
  float st[64];
#pragma unroll
  for (int s = 0; s < 64; s++) st[s] = 0.f;
  size_t base = ((size_t)b * T_ + (size_t)c * CHL) * C_ + h * 64 + lane;
  const u16* Kp = Kb + base;
  const u16* Vp = Vb + base;
  for (int t = 0; t < CHL; t++) {
    float kcur = bf2f(Kp[(size_t)t * C_]), vcur = bf2f(Vp[(size_t)t * C_]);
#pragma unroll
    for (int s = 0; s < 64; s++) {
      float ks = __shfl(kcur, s);
      st[s] = fmaf(wreg[s], st[s], ks * vcur);
    }
  }
  float* outp = chunks + (((size_t)c * B_ + b) * H_ + h) * 4096 + lane;
#pragma unroll
  for (int s = 0; s < 64; s++) outp[s * 64] = st[s];
}

// ---------------- scan phase 2 ----------------
template <int NCH, int CHL>
__global__ __launch_bounds__(256) void scan_phase2(
    const float* __restrict__ st0, const float* __restrict__ td,
    float* __restrict__ chunks, float* __restrict__ state_out) {
  int idx = blockIdx.x * 256 + threadIdx.x;
  int h = (idx >> 12) & 31;
  int s = (idx >> 6) & 63;
  float wL = __expf(-(float)CHL * __expf(td[h * 64 + s]));
  float st = st0[idx];
#pragma unroll
  for (int cc = 0; cc < NCH; cc++) {
    size_t off = (size_t)cc * 524288 + idx;
    float sc = chunks[off];
    chunks[off] = st;
    st = fmaf(wL, st, sc);
  }
  state_out[idx] = st;
}

// ---------------- scan phase 3 (MFMA, 4-wave blocks, CHL=64) ----------------
__global__ __launch_bounds__(256) void scan_phase3_mfma(
    const u16* __restrict__ Rb, const u16* __restrict__ Kb,
    const u16* __restrict__ Vb, const float* __restrict__ td,
    const float* __restrict__ tf, const float* __restrict__ chunks,
    const u16* __restrict__ Gb, const float* __restrict__ lnw,
    const float* __restrict__ lnb, u16* __restrict__ Y) {
  __shared__ __align__(16) u16 smem[4][5248];
  int lane = threadIdx.x & 63, wib = threadIdx.x >> 6;
  int gw = blockIdx.x * 4 + wib;
  int c = gw & 31, bh = gw >> 5;
  int h = bh & 31, b = bh >> 5;
  int a = lane & 15, g = lane >> 4;
  int h0 = h * 64;

  u16* Kt = smem[wib];
  u16* Vt = Kt + 1024;
  u16* StT = Vt + 1024;
  u16* AT = StT + 2560;

  f32x8 sA[2], sB[2], sC[2], uA[2];
#pragma unroll
  for (int kk = 0; kk < 2; kk++) {
#pragma unroll
    for (int e = 0; e < 8; e++) {
      int s = kk * 32 + g * 8 + e;
      float ew = __expf(td[h0 + s]);
      sA[kk][e] = __expf(-(float)a * ew);
      sB[kk][e] = __expf(-((float)a - 8.f) * ew);
      sC[kk][e] = __expf(-(7.f - (float)a) * ew);
      uA[kk][e] = tf[h0 + s];
    }
  }
  f32x4 sE[4];
  f32x4 ewD;
#pragma unroll
  for (int ms = 0; ms < 4; ms++) {
    ewD[ms] = __expf(td[h0 + ms * 16 + a]);
#pragma unroll
    for (int q = 0; q < 4; q++)
      sE[ms][q] = __expf(-16.f * __expf(td[h0 + ms * 16 + g * 4 + q]));
  }
  float lwv[4], lbv[4];
#pragma unroll
  for (int nd = 0; nd < 4; nd++) {
    lwv[nd] = lnw[h0 + nd * 16 + a];
    lbv[nd] = lnb[h0 + nd * 16 + a];
  }

  f32x4 St[4][4];
  const float* cpc = chunks + (((size_t)c * B_ + b) * H_ + h) * 4096;
#pragma unroll
  for (int ms = 0; ms < 4; ms++)
#pragma unroll
    for (int nd = 0; nd < 4; nd++)
#pragma unroll
      for (int q = 0; q < 4; q++)
        St[ms][nd][q] = cpc[(size_t)(ms * 16 + g * 4 + q) * 64 + nd * 16 + a];

#pragma unroll
  for (int z = 0; z < 6; z++) {
    int idx = z * 64 + lane;
    int row = idx / 24, col = 16 + idx % 24;
    AT[row * 40 + col] = 0;
  }

  size_t tbase = ((size_t)b * T_ + (size_t)c * 64) * C_ + h0;

  for (int sb = 0; sb < 4; sb++) {
    size_t rb0 = tbase + (size_t)(sb * 16) * C_;

    ushort8v r8[2], k8[2];
#pragma unroll
    for (int kk = 0; kk < 2; kk++) {
      r8[kk] = *reinterpret_cast<const ushort8v*>(Rb + rb0 + (size_t)a * C_ + kk * 32 + g * 8);
      k8[kk] = *reinterpret_cast<const ushort8v*>(Kb + rb0 + (size_t)a * C_ + kk * 32 + g * 8);
    }
    {
      int srow = lane >> 3;
      int scol = (lane & 7) * 8;
      *reinterpret_cast<ushort8v*>(&Kt[srow * 64 + scol]) =
          *reinterpret_cast<const ushort8v*>(Kb + rb0 + (size_t)srow * C_ + scol);
      *reinterpret_cast<ushort8v*>(&Kt[(srow + 8) * 64 + scol]) =
          *reinterpret_cast<const ushort8v*>(Kb + rb0 + (size_t)(srow + 8) * C_ + scol);
      *reinterpret_cast<ushort8v*>(&Vt[srow * 64 + scol]) =
          *reinterpret_cast<const ushort8v*>(Vb + rb0 + (size_t)srow * C_ + scol);
      *reinterpret_cast<ushort8v*>(&Vt[(srow + 8) * 64 + scol]) =
          *reinterpret_cast<const ushort8v*>(Vb + rb0 + (size_t)(srow + 8) * C_ + scol);
    }

    f32x4 O[4];
#pragma unroll
    for (int nd = 0; nd < 4; nd++) O[nd] = (f32x4){0.f, 0.f, 0.f, 0.f};

#pragma unroll
    for (int kk = 0; kk < 2; kk++) {
#pragma unroll
      for (int msl = 0; msl < 2; msl++) {
        int ms = kk * 2 + msl;
#pragma unroll
        for (int nd = 0; nd < 4; nd++) {
          ushort4 pk;
          pk.x = f2bf(St[ms][nd][0]); pk.y = f2bf(St[ms][nd][1]);
          pk.z = f2bf(St[ms][nd][2]); pk.w = f2bf(St[ms][nd][3]);
          *reinterpret_cast<ushort4*>(&StT[(a + nd * 16) * 40 + msl * 16 + g * 4]) = pk;
        }
      }
      ushort8v rt;
#pragma unroll
      for (int e = 0; e < 8; e++) rt[e] = f2bf(bf2f(r8[kk][e]) * sA[kk][e]);
      bf16x8 rtf = __builtin_bit_cast(bf16x8, rt);
#pragma unroll
      for (int nd = 0; nd < 4; nd++) {
        ushort8v sfr = *reinterpret_cast<const ushort8v*>(&StT[(a + nd * 16) * 40 + g * 8]);
        O[nd] = __builtin_amdgcn_mfma_f32_16x16x32_bf16(
            rtf, __builtin_bit_cast(bf16x8, sfr), O[nd], 0, 0, 0);
      }
    }

    float p = 0.f;
#pragma unroll
    for (int kk = 0; kk < 2; kk++)
#pragma unroll
      for (int e = 0; e < 8; e++)
        p = fmaf(bf2f(r8[kk][e]) * uA[kk][e], bf2f(k8[kk][e]), p);
    p += __shfl_xor(p, 16);
    p += __shfl_xor(p, 32);

    f32x4 Am = (f32x4){0.f, 0.f, 0.f, 0.f};
#pragma unroll
    for (int kk = 0; kk < 2; kk++) {
      ushort8v kh, rh;
#pragma unroll
      for (int e = 0; e < 8; e++) {
        kh[e] = f2bf(bf2f(k8[kk][e]) * sC[kk][e]);
        rh[e] = f2bf(bf2f(r8[kk][e]) * sB[kk][e]);
      }
      Am = __builtin_amdgcn_mfma_f32_16x16x32_bf16(
          __builtin_bit_cast(bf16x8, kh), __builtin_bit_cast(bf16x8, rh), Am, 0, 0, 0);
    }
    {
      ushort4 aw;
#pragma unroll
      for (int q = 0; q < 4; q++) {
        int jr = g * 4 + q;
        float v = (jr < a) ? Am[q] : ((jr == a) ? p : 0.f);
        ((u16*)&aw)[q] = f2bf(v);
      }
      *reinterpret_cast<ushort4*>(&AT[a * 40 + g * 4]) = aw;
    }
    bf16x8 afrag;
    {
      ushort8v t8 = *reinterpret_cast<const ushort8v*>(&AT[a * 40 + g * 8]);
      afrag = __builtin_bit_cast(bf16x8, t8);
    }

    bf16x8 vfrag[4];
#pragma unroll
    for (int nd = 0; nd < 4; nd++) {
      ushort8v t8;
      if (g < 2) {
#pragma unroll
        for (int e = 0; e < 8; e++) t8[e] = Vt[(g * 8 + e) * 64 + a + nd * 16];
      } else {
#pragma unroll
        for (int e = 0; e < 8; e++) t8[e] = 0;
      }
      vfrag[nd] = __builtin_bit_cast(bf16x8, t8);
    }

#pragma unroll
    for (int nd = 0; nd < 4; nd++)
      O[nd] = __builtin_amdgcn_mfma_f32_16x16x32_bf16(afrag, vfrag[nd], O[nd], 0, 0, 0);

#pragma unroll
    for (int ms = 0; ms < 4; ms++)
#pragma unroll
      for (int nd = 0; nd < 4; nd++)
#pragma unroll
        for (int q = 0; q < 4; q++) St[ms][nd][q] *= sE[ms][q];

#pragma unroll
    for (int ms = 0; ms < 4; ms++) {
      ushort8v kt8;
      if (g < 2) {
#pragma unroll
        for (int e = 0; e < 8; e++) {
          int j = g * 8 + e;
          float f = bf2f(Kt[j * 64 + ms * 16 + a]) * __expf(-(15.f - (float)j) * ewD[ms]);
          kt8[e] = f2bf(f);
        }
      } else {
#pragma unroll
        for (int e = 0; e < 8; e++) kt8[e] = 0;
      }
      bf16x8 kf = __builtin_bit_cast(bf16x8, kt8);
#pragma unroll
      for (int nd = 0; nd < 4; nd++)
        St[ms][nd] = __builtin_amdgcn_mfma_f32_16x16x32_bf16(kf, vfrag[nd], St[ms][nd], 0, 0, 0);
    }

#pragma unroll
    for (int nd = 0; nd < 4; nd++)
#pragma unroll
      for (int q = 0; q < 4; q++) O[nd][q] *= 0.125f;
#pragma unroll
    for (int q = 0; q < 4; q++) {
      float ssum = O[0][q] + O[1][q] + O[2][q] + O[3][q];
      ssum += __shfl_xor(ssum, 1); ssum += __shfl_xor(ssum, 2);
      ssum += __shfl_xor(ssum, 4); ssum += __shfl_xor(ssum, 8);
      float mean = ssum * (1.f / 64.f);
      float vv = 0.f;
#pragma unroll
      for (int nd = 0; nd < 4; nd++) {
        float d = O[nd][q] - mean;
        vv = fmaf(d, d, vv);
      }
      vv += __shfl_xor(vv, 1); vv += __shfl_xor(vv, 2);
      vv += __shfl_xor(vv, 4); vv += __shfl_xor(vv, 8);
      float rs = rsqrtf(vv * (1.f / 64.f) + 1e-5f);
      size_t rowoff = rb0 + (size_t)(g * 4 + q) * C_;
#pragma unroll
      for (int nd = 0; nd < 4; nd++) {
        float xn = (O[nd][q] - mean) * rs;
        float gv = bf2f(Gb[rowoff + nd * 16 + a]);
        float sg = gv / (1.f + __expf(-gv));
        Y[rowoff + nd * 16 + a] = f2bf((xn * lwv[nd] + lbv[nd]) * sg);
      }
    }
  }
}

// ---------------- scan phase 3 (scalar fallback, NCH16) ----------------
template <int NCH, int CHL>
__global__ __launch_bounds__(256) void scan_phase3(
    const u16* __restrict__ Rb, const u16* __restrict__ Kb,
    const u16* __restrict__ Vb, const float* __restrict__ td,
    const float* __restrict__ tf, const float* __restrict__ chunks,
    const u16* __restrict__ Gb, const float* __restrict__ lnw,
    const float* __restrict__ lnb, u16* __restrict__ Y) {
  int lane = threadIdx.x & 63;
  int gw = (blockIdx.x * 256 + threadIdx.x) >> 6;
  int c = gw & (NCH - 1), bh = gw / NCH;
  int h = bh & 31, b = bh >> 5;
  const float* tdh = td + h * 64;
  float wreg[64];
#pragma unroll
  for (int s = 0; s < 64; s++) wreg[s] = __expf(-__expf(tdh[s]));
  float u_own = tf[h * 64 + lane];
  float lw = lnw[h * 64 + lane];
  float lb = lnb[h * 64 + lane];
  float st[64];
  const float* cp = chunks + (((size_t)c * B_ + b) * H_ + h) * 4096 + lane;
#pragma unroll
  for (int s = 0; s < 64; s++) st[s] = cp[s * 64];
  size_t base = ((size_t)b * T_ + (size_t)c * CHL) * C_ + h * 64 + lane;
  const u16* Rp = Rb + base;
  const u16* Kp = Kb + base;
  const u16* Vp = Vb + base;
  const u16* Gp = Gb + base;
  u16* Yp = Y + base;
  for (int t = 0; t < CHL; t++) {
    float rcur = bf2f(Rp[(size_t)t * C_]);
    float kcur = bf2f(Kp[(size_t)t * C_]);
    float vcur = bf2f(Vp[(size_t)t * C_]);
    float p = rcur * u_own * kcur;
#pragma unroll
    for (int off = 32; off >= 1; off >>= 1) p += __shfl_xor(p, off);
    float acc = 0.f;
#pragma unroll
    for (int s = 0; s < 64; s++) {
      float rs = __shfl(rcur, s);
      float ks = __shfl(kcur, s);
      acc = fmaf(rs, st[s], acc);
      st[s] = fmaf(wreg[s], st[s], ks * vcur);
    }
    float o = fmaf(p, vcur, acc);
    float x = o * 0.125f;
    float sum = x;
#pragma unroll
    for (int off = 32; off >= 1; off >>= 1) sum += __shfl_xor(sum, off);
    float mean = sum * (1.f / 64.f);
    float d = x - mean;
    float v2 = d * d;
#pragma unroll
    for (int off = 32; off >= 1; off >>= 1) v2 += __shfl_xor(v2, off);
    float var = v2 * (1.f / 64.f);
    float xn = d * rsqrtf(var + 1e-5f);
    float gg = bf2f(Gp[(size_t)t * C_]);
    float sg = gg / (1.f + __expf(-gg));
    Yp[(size_t)t * C_] = f2bf((xn * lw + lb) * sg);
  }
}

extern "C" void kernel_launch(void* const* d_in, const int* in_sizes, int n_in,
                              void* d_out, int out_size, void* d_ws, size_t ws_size,
                              hipStream_t stream) {
  const float* hidden = (const float*)d_in[0];
  const float* state0 = (const float*)d_in[1];
  const float* td = (const float*)d_in[2];
  const float* tf = (const float*)d_in[3];
  const float* mk = (const float*)d_in[4];
  const float* mv = (const float*)d_in[5];
  const float* mr = (const float*)d_in[6];
  const float* mg = (const float*)d_in[7];
  const float* kw = (const float*)d_in[8];
  const float* vw = (const float*)d_in[9];
  const float* rw = (const float*)d_in[10];
  const float* gw = (const float*)d_in[11];
  const float* ow = (const float*)d_in[12];
  const float* lnw = (const float*)d_in[13];
  const float* lnb = (const float*)d_in[14];

  float* out = (float*)d_out;
  float* state_f = out + (size_t)B_ * T_ * C_;

  const size_t BUF = (size_t)B_ * T_ * C_ * 2;       // 33,554,432 B
  const size_t WBUF = (size_t)C_ * C_ * 2;           // 8,388,608 B
  const size_t needOpt = 7 * BUF + WBUF;             // 243,269,632 B

  dim3 blk(256);
  int mixGrid = (B_ * T_ * C_ / 4) / 256;
  int convN4 = C_ * C_ / 4;
  int convGrid = convN4 / 256;
  int gemmGrid = (B_ * T_ / 256) * (C_ / 256);
  dim3 gblk(512);

  if (ws_size >= needOpt) {
    char* base = (char*)d_ws;
    u16* mixG = (u16*)(base + 0 * BUF);          // A
    u16* mixR = (u16*)(base + 1 * BUF);          // B
    u16* mixK = (u16*)(base + 2 * BUF);          // C
    u16* mixV = (u16*)(base + 3 * BUF);          // D
    u16* wb   = (u16*)(base + 4 * BUF);
    u16* gb   = (u16*)(base + 4 * BUF + WBUF);
    u16* kb   = (u16*)(base + 5 * BUF + WBUF);
    u16* vb   = (u16*)(base + 6 * BUF + WBUF);
    u16* rb   = mixG;                            // alias A (dead after G-gemm)
    u16* Y    = mixR;                            // alias B (dead after R-gemm)
    float* chunks = (float*)(base + 2 * BUF);    // alias C+D (dead after K,V-gemms)
    // weight stashes in regions dead until their consuming gemm:
    u16* rwS = kb;   // kb first written at K-gemm (#3); rw read at R-gemm (#2)
    u16* kwS = vb;   // vb first written at V-gemm (#4); kw read at K-gemm (#3)

    mix4p_cast_kernel<<<B_ * T_, blk, 0, stream>>>(hidden, mk, mv, mr, mg,
                                                   mixK, mixV, mixR, mixG);
    conv3_bf16_kernel<<<3 * convGrid, blk, 0, stream>>>(gw, rw, kw, wb, rwS, kwS);
    gemm_bt256<u16><<<gemmGrid, gblk, 0, stream>>>(mixG, wb, gb, B_ * T_, C_, C_);
    gemm_bt256<u16><<<gemmGrid, gblk, 0, stream>>>(mixR, rwS, rb, B_ * T_, C_, C_);
    gemm_bt256<u16><<<gemmGrid, gblk, 0, stream>>>(mixK, kwS, kb, B_ * T_, C_, C_);
    conv_bf16_kernel<<<convGrid, blk, 0, stream>>>(vw, wb, convN4);
    gemm_bt256<u16><<<gemmGrid, gblk, 0, stream>>>(mixV, wb, vb, B_ * T_, C_, C_);

    scan_phase1_mfma<64><<<B_ * H_ * 32, dim3(64), 0, stream>>>(kb, vb, td, chunks);
    scan_phase2<32, 64><<<2048, blk, 0, stream>>>(state0, td, chunks, state_f);
    scan_phase3_mfma<<<(B_ * H_ * 32) / 4, blk, 0, stream>>>(rb, kb, vb, td, tf, chunks, gb, lnw, lnb, Y);

    conv_bf16_kernel<<<convGrid, blk, 0, stream>>>(ow, wb, convN4);
    gemm_bt256<float><<<gemmGrid, gblk, 0, stream>>>(Y, wb, out, B_ * T_, C_, C_);
    return;
  }

  // minimal fallback (~209.7 MB): NCH16 scalar scans, serialized mixes
  char* ws = (char*)d_ws;
  u16* mixA = (u16*)ws;    ws += BUF;
  u16* wb = (u16*)ws;      ws += WBUF;
  u16* rb = (u16*)ws;      ws += BUF;
  u16* kb = (u16*)ws;      ws += BUF;
  u16* vb = (u16*)ws;      ws += BUF;
  u16* gb = (u16*)ws;      ws += BUF;
  float* chunks = (float*)ws;

  mix_cast_kernel<<<mixGrid, blk, 0, stream>>>(hidden, mr, mixA);
  conv_bf16_kernel<<<convGrid, blk, 0, stream>>>(rw, wb, convN4);
  gemm_bt256<u16><<<gemmGrid, gblk, 0, stream>>>(mixA, wb, rb, B_ * T_, C_, C_);
  mix_cast_kernel<<<mixGrid, blk, 0, stream>>>(hidden, mk, mixA);
  conv_bf16_kernel<<<convGrid, blk, 0, stream>>>(kw, wb, convN4);
  gemm_bt256<u16><<<gemmGrid, gblk, 0, stream>>>(mixA, wb, kb, B_ * T_, C_, C_);
  mix_cast_kernel<<<mixGrid, blk, 0, stream>>>(hidden, mv, mixA);
  conv_bf16_kernel<<<convGrid, blk, 0, stream>>>(vw, wb, convN4);
  gemm_bt256<u16><<<gemmGrid, gblk, 0, stream>>>(mixA, wb, vb, B_ * T_, C_, C_);
  mix_cast_kernel<<<mixGrid, blk, 0, stream>>>(hidden, mg, mixA);
  conv_bf16_kernel<<<convGrid, blk, 0, stream>>>(gw, wb, convN4);
  gemm_bt256<u16><<<gemmGrid, gblk, 0, stream>>>(mixA, wb, gb, B_ * T_, C_, C_);

  scan_phase1<16, 128><<<(B_ * H_ * 16) / 4, blk, 0, stream>>>(kb, vb, td, chunks);
  scan_phase2<16, 128><<<2048, blk, 0, stream>>>(state0, td, chunks, state_f);
  scan_phase3<16, 128><<<(B_ * H_ * 16) / 4, blk, 0, stream>>>(rb, kb, vb, td, tf, chunks, gb, lnw, lnb, mixA);

  conv_bf16_kernel<<<convGrid, blk, 0, stream>>>(ow, wb, convN4);
  gemm_bt256<float><<<gemmGrid, gblk, 0, stream>>>(mixA, wb, out, B_ * T_, C_, C_);
}